// Round 10
// baseline (819.996 us; speedup 1.0000x reference)
//
#include <hip/hip_runtime.h>
#include <hip/hip_bf16.h>
#include <math.h>

typedef __hip_bfloat16 bf16;

#define MROWS 4096      // BATCH * L
#define DMODEL 384
#define DINNER 768
#define GCOLS 56        // DT_RANK + 2*D_STATE
#define DTRANK 24
#define NSTATE 16
#define NCHUNK 32
#define TCHUNK 32

typedef __attribute__((ext_vector_type(8))) short bf16x8;
typedef __attribute__((ext_vector_type(4))) float f32x4;

#if __has_builtin(__builtin_amdgcn_exp2f)
#define EXP2F(x) __builtin_amdgcn_exp2f(x)
#else
#define EXP2F(x) exp2f(x)
#endif

__device__ __forceinline__ float silu_f(float x){ return x / (1.f + __expf(-x)); }
__device__ __forceinline__ float softplus_f(float x){
  return (x > 20.f) ? x : __logf(1.f + __expf(x));
}
__device__ __forceinline__ short f2bs(float x){
  bf16 h = __float2bfloat16(x);
  return *(short*)&h;
}
__device__ __forceinline__ float bs2f(short s){
  bf16 h = *(bf16*)&s;
  return __bfloat162float(h);
}

// seq index t -> token index, per direction
__device__ __forceinline__ int perm_tok(int dir, int t){
  if (dir == 0) return t;
  if (dir == 2) return 1023 - t;
  int tt = (dir == 1) ? t : (1023 - t);
  int i = tt >> 5, j = tt & 31;
  return ((31 - j) << 5) | i;   // token = (31-j)*32 + i
}

// A2[n] = -exp(A_log[n])*log2e ; geo==true iff A2[n] == (n+1)*A2[0] (this dataset: yes)
__device__ __forceinline__ bool load_A2(const float* __restrict__ A_log, int d, float* A2){
  bool geo = true;
#pragma unroll
  for (int n=0;n<NSTATE;n++){
    A2[n] = -__expf(A_log[d*NSTATE + n]) * 1.44269504f;
  }
#pragma unroll
  for (int n=1;n<NSTATE;n++){
    float pred = (float)(n+1) * A2[0];
    geo = geo && (fabsf(A2[n] - pred) <= 1e-4f*fabsf(A2[n]) + 1e-6f);
  }
  return geo;
}

// ---------------- bf16 MFMA GEMM: C[M,N] = A[M,K] @ W[N,K]^T (fp32 accum) ----
// EPI 0: none (fp32 out); 2: + bias[n] + res[m,n] (fp32 out)
template<int EPI>
__launch_bounds__(256)
__global__ void gemm_mfma_k(const short* __restrict__ A, int lda,
                            const short* __restrict__ W, int ldw,
                            float* __restrict__ C, int ldc,
                            int Ndim, int Kdim,
                            const float* __restrict__ bias,
                            const float* __restrict__ res)
{
  const int wv = threadIdx.x >> 6, lane = threadIdx.x & 63;
  const int m0 = blockIdx.y * 64;
  const int n0 = blockIdx.x * 64 + wv * 16;
  const int lm = lane & 15;          // fragment row (A-m / B-n)
  const int kq = (lane >> 4) * 8;    // fragment k offset
  f32x4 acc0 = {0.f,0.f,0.f,0.f}, acc1 = acc0, acc2 = acc0, acc3 = acc0;
  const bool nok = (n0 + lm) < Ndim;
  const short* ap = A + (size_t)(m0 + lm) * lda + kq;
  const short* wp = W + (size_t)(nok ? (n0 + lm) : 0) * ldw + kq;
  const size_t ar16 = (size_t)16 * lda;
  const bf16x8 bz = {0,0,0,0,0,0,0,0};

  for (int k0 = 0; k0 < Kdim; k0 += 32) {
    bf16x8 b = bz;
    if (nok) b = *(const bf16x8*)(wp + k0);
    bf16x8 a0 = *(const bf16x8*)(ap + k0);
    bf16x8 a1 = *(const bf16x8*)(ap + ar16 + k0);
    bf16x8 a2 = *(const bf16x8*)(ap + 2*ar16 + k0);
    bf16x8 a3 = *(const bf16x8*)(ap + 3*ar16 + k0);
    acc0 = __builtin_amdgcn_mfma_f32_16x16x32_bf16(a0, b, acc0, 0, 0, 0);
    acc1 = __builtin_amdgcn_mfma_f32_16x16x32_bf16(a1, b, acc1, 0, 0, 0);
    acc2 = __builtin_amdgcn_mfma_f32_16x16x32_bf16(a2, b, acc2, 0, 0, 0);
    acc3 = __builtin_amdgcn_mfma_f32_16x16x32_bf16(a3, b, acc3, 0, 0, 0);
  }

  const int ncol = n0 + lm;                 // C/D: col = lane&15
  if (ncol < Ndim) {
    const int mr = m0 + (lane >> 4) * 4;    // C/D: row = quad*4 + reg
    f32x4 av[4] = {acc0, acc1, acc2, acc3};
#pragma unroll
    for (int mt = 0; mt < 4; mt++) {
#pragma unroll
      for (int reg = 0; reg < 4; reg++) {
        int m = mr + mt*16 + reg;
        float v = av[mt][reg];
        if (EPI == 2) v += bias[ncol] + res[(size_t)m*ldc + ncol];
        C[(size_t)m*ldc + ncol] = v;
      }
    }
  }
}

// same GEMM but bf16 output (for in_proj -> xz_b)
__launch_bounds__(256)
__global__ void gemm_mfma_bout_k(const short* __restrict__ A, int lda,
                                 const short* __restrict__ W, int ldw,
                                 short* __restrict__ C, int ldc,
                                 int Ndim, int Kdim)
{
  const int wv = threadIdx.x >> 6, lane = threadIdx.x & 63;
  const int m0 = blockIdx.y * 64;
  const int n0 = blockIdx.x * 64 + wv * 16;
  const int lm = lane & 15;
  const int kq = (lane >> 4) * 8;
  f32x4 acc0 = {0.f,0.f,0.f,0.f}, acc1 = acc0, acc2 = acc0, acc3 = acc0;
  const bool nok = (n0 + lm) < Ndim;
  const short* ap = A + (size_t)(m0 + lm) * lda + kq;
  const short* wp = W + (size_t)(nok ? (n0 + lm) : 0) * ldw + kq;
  const size_t ar16 = (size_t)16 * lda;
  const bf16x8 bz = {0,0,0,0,0,0,0,0};

  for (int k0 = 0; k0 < Kdim; k0 += 32) {
    bf16x8 b = bz;
    if (nok) b = *(const bf16x8*)(wp + k0);
    bf16x8 a0 = *(const bf16x8*)(ap + k0);
    bf16x8 a1 = *(const bf16x8*)(ap + ar16 + k0);
    bf16x8 a2 = *(const bf16x8*)(ap + 2*ar16 + k0);
    bf16x8 a3 = *(const bf16x8*)(ap + 3*ar16 + k0);
    acc0 = __builtin_amdgcn_mfma_f32_16x16x32_bf16(a0, b, acc0, 0, 0, 0);
    acc1 = __builtin_amdgcn_mfma_f32_16x16x32_bf16(a1, b, acc1, 0, 0, 0);
    acc2 = __builtin_amdgcn_mfma_f32_16x16x32_bf16(a2, b, acc2, 0, 0, 0);
    acc3 = __builtin_amdgcn_mfma_f32_16x16x32_bf16(a3, b, acc3, 0, 0, 0);
  }

  const int ncol = n0 + lm;
  if (ncol < Ndim) {
    const int mr = m0 + (lane >> 4) * 4;
    f32x4 av[4] = {acc0, acc1, acc2, acc3};
#pragma unroll
    for (int mt = 0; mt < 4; mt++) {
#pragma unroll
      for (int reg = 0; reg < 4; reg++) {
        int m = mr + mt*16 + reg;
        C[(size_t)m*ldc + ncol] = f2bs(av[mt][reg]);
      }
    }
  }
}

// ---------------- conversions / misc ----------------
__global__ void f2b5_k(const float* __restrict__ a0, const float* __restrict__ a1,
                       const float* __restrict__ a2, const float* __restrict__ a3,
                       const float* __restrict__ a4, short* __restrict__ o,
                       int s0, int s1, int s2, int s3, int s4)
{
  int id = blockIdx.x*256 + threadIdx.x;
  int e0 = s0, e1 = e0+s1, e2 = e1+s2, e3 = e2+s3, e4 = e3+s4;
  if (id >= e4) return;
  float v;
  if      (id < e0) v = a0[id];
  else if (id < e1) v = a1[id-e0];
  else if (id < e2) v = a2[id-e1];
  else if (id < e3) v = a3[id-e2];
  else              v = a4[id-e3];
  o[id] = f2bs(v);
}
__global__ void cvt_dual_k(const float* __restrict__ in, float* __restrict__ of,
                           short* __restrict__ ob, int n){
  int id = blockIdx.x*256 + threadIdx.x;
  if (id < n) { float v = in[id]; of[id] = v; ob[id] = f2bs(v); }
}

// depthwise causal conv (k=4) over permuted sequence + bias + silu; bf16 in/out
__launch_bounds__(256)
__global__ void conv_k(const short* __restrict__ xzb, const float* __restrict__ cw,
                       const float* __restrict__ cb, short* __restrict__ ucv_b)
{
  int id = blockIdx.x*256 + threadIdx.x;          // ((dir*4+b)*1024+t)*768+d
  int d = id % DINNER;
  int t = (id / DINNER) & 1023;
  int btdir = id / (DINNER*1024);
  int b_ = btdir & 3, dir = btdir >> 2;
  float s = cb[d];
  const short* up = xzb + (size_t)b_*1024*1536 + d;
#pragma unroll
  for (int j=0;j<4;j++){
    int tm = t - 3 + j;
    if (tm >= 0) s += cw[d*4+j] * bs2f(up[(size_t)perm_tok(dir,tm)*1536]);
  }
  ucv_b[id] = f2bs(silu_f(s));
}

// ============ chunked selective scan (dt fused, geometric-decay fast path) ============
// Pass A: grid (3, NCHUNK, 16): local scan from 0 -> hL[n]; accumulate sum_dt
__launch_bounds__(256)
__global__ void chunk_scan_k(const short* __restrict__ ucv_b,
                             const float* __restrict__ xdb, const float* __restrict__ A_log,
                             const float* __restrict__ dt_w, const float* __restrict__ dt_b,
                             float* __restrict__ sums, float* __restrict__ hLb)
{
  const int d  = blockIdx.x * 256 + threadIdx.x;   // 0..767
  const int c  = blockIdx.y;                       // chunk
  const int bd = blockIdx.z;                       // dir*4+b

  float A2[NSTATE];
  const bool geo = load_A2(A_log, d, A2);
  float w24[DTRANK];
#pragma unroll
  for (int r=0;r<DTRANK;r++) w24[r] = dt_w[d*DTRANK + r];
  const float bias = dt_b[d];

  const size_t rowbase = (size_t)bd*1024 + (size_t)c*TCHUNK;
  const short* up  = ucv_b + rowbase*DINNER + d;
  const float* bc  = xdb + rowbase*GCOLS;            // block-uniform

  float h[NSTATE] = {};
  float sdt = 0.f;

  for (int tg=0; tg<TCHUNK; tg+=4){
    float u4[4];
#pragma unroll
    for (int q=0;q<4;q++)
      u4[q]  = bs2f(up[(size_t)(tg+q)*DINNER]);
#pragma unroll
    for (int q=0;q<4;q++){
      const float* Xr = bc + (tg+q)*GCOLS;           // uniform -> s_load
      float v = bias;
#pragma unroll
      for (int r=0;r<DTRANK;r++) v = __builtin_fmaf(Xr[r], w24[r], v);
      float dt = softplus_f(v);
      const float* Bv = Xr + DTRANK;
      float4 B0 = *(const float4*)(Bv+0), B1 = *(const float4*)(Bv+4);
      float4 B2 = *(const float4*)(Bv+8), B3 = *(const float4*)(Bv+12);
      float Bf[NSTATE] = {B0.x,B0.y,B0.z,B0.w, B1.x,B1.y,B1.z,B1.w,
                          B2.x,B2.y,B2.z,B2.w, B3.x,B3.y,B3.z,B3.w};
      float du = dt*u4[q];
      sdt += dt;
      if (geo){
        float w1 = EXP2F(dt * A2[0]);
        float wacc = w1;
        h[0] = h[0]*wacc + du*Bf[0];
#pragma unroll
        for (int n=1;n<NSTATE;n++){
          wacc *= w1;
          h[n] = h[n]*wacc + du * Bf[n];
        }
      } else {
#pragma unroll
        for (int n=0;n<NSTATE;n++){
          float w = EXP2F(dt * A2[n]);
          h[n] = h[n]*w + du * Bf[n];
        }
      }
    }
  }
  size_t ob = ((size_t)(bd*NCHUNK + c) * NSTATE) * DINNER + d;
#pragma unroll
  for (int n=0;n<NSTATE;n++)
    hLb[ob + (size_t)n*DINNER] = h[n];
  sums[(size_t)(bd*NCHUNK + c)*DINNER + d] = sdt;
}

// Pass B: serial combine over chunks; W reconstructed from sum_dt; hLb -> chunk-initial h0
__launch_bounds__(256)
__global__ void chunk_comb_k(const float* __restrict__ sums, const float* __restrict__ A_log,
                             float* __restrict__ hLb)
{
  int id = blockIdx.x*256 + threadIdx.x;    // (dir*4+b)*768+d
  int d = id % DINNER;
  int bd = id / DINNER;
  float A2[NSTATE];
  const bool geo = load_A2(A_log, d, A2);
  float h[NSTATE] = {};
  for (int c=0; c<NCHUNK; c++){
    size_t ob = ((size_t)(bd*NCHUNK + c) * NSTATE) * DINNER + d;
    float sdt = sums[(size_t)(bd*NCHUNK + c)*DINNER + d];
    if (geo){
      float w1 = EXP2F(A2[0] * sdt);
      float wacc = 1.f;
#pragma unroll
      for (int n=0;n<NSTATE;n++){
        wacc *= w1;
        float hL = hLb[ob + (size_t)n*DINNER];
        float h0 = h[n];
        h[n] = wacc*h0 + hL;
        hLb[ob + (size_t)n*DINNER] = h0;
      }
    } else {
#pragma unroll
      for (int n=0;n<NSTATE;n++){
        float Wc = EXP2F(A2[n] * sdt);
        float hL = hLb[ob + (size_t)n*DINNER];
        float h0 = h[n];
        h[n] = Wc*h0 + hL;
        hLb[ob + (size_t)n*DINNER] = h0;
      }
    }
  }
}

// Pass C: replay from h0, emit y, scatter-add token-space (dt fused)
__launch_bounds__(256)
__global__ void chunk_emit_k(const short* __restrict__ ucv_b,
                             const float* __restrict__ xdb, const float* __restrict__ A_log,
                             const float* __restrict__ dt_w, const float* __restrict__ dt_b,
                             const float* __restrict__ Dp, const float* __restrict__ h0b,
                             float* __restrict__ acc)
{
  const int d  = blockIdx.x * 256 + threadIdx.x;
  const int c  = blockIdx.y;
  const int bd = blockIdx.z;
  const int b  = bd & 3, dir = bd >> 2;

  float A2[NSTATE];
  const bool geo = load_A2(A_log, d, A2);
  float w24[DTRANK];
#pragma unroll
  for (int r=0;r<DTRANK;r++) w24[r] = dt_w[d*DTRANK + r];
  const float bias = dt_b[d];
  float Dd = Dp[d];

  const size_t rowbase = (size_t)bd*1024 + (size_t)c*TCHUNK;
  const short* up  = ucv_b + rowbase*DINNER + d;
  const float* bc  = xdb + rowbase*GCOLS;            // block-uniform
  float* ab = acc + (size_t)b*1024*DINNER + d;

  float h[NSTATE];
  size_t ob = ((size_t)(bd*NCHUNK + c) * NSTATE) * DINNER + d;
#pragma unroll
  for (int n=0;n<NSTATE;n++) h[n] = h0b[ob + (size_t)n*DINNER];

  const int t0 = c * TCHUNK;
  for (int tg=0; tg<TCHUNK; tg+=4){
    float u4[4];
#pragma unroll
    for (int q=0;q<4;q++)
      u4[q]  = bs2f(up[(size_t)(tg+q)*DINNER]);
#pragma unroll
    for (int q=0;q<4;q++){
      const float* Xr = bc + (tg+q)*GCOLS;           // uniform -> s_load
      float v = bias;
#pragma unroll
      for (int r=0;r<DTRANK;r++) v = __builtin_fmaf(Xr[r], w24[r], v);
      float dt = softplus_f(v);
      const float* Bv = Xr + DTRANK;
      float4 B0 = *(const float4*)(Bv+0), B1 = *(const float4*)(Bv+4);
      float4 B2 = *(const float4*)(Bv+8), B3 = *(const float4*)(Bv+12);
      float4 C0 = *(const float4*)(Bv+16), C1 = *(const float4*)(Bv+20);
      float4 C2 = *(const float4*)(Bv+24), C3 = *(const float4*)(Bv+28);
      float Bf[NSTATE] = {B0.x,B0.y,B0.z,B0.w, B1.x,B1.y,B1.z,B1.w,
                          B2.x,B2.y,B2.z,B2.w, B3.x,B3.y,B3.z,B3.w};
      float Cf[NSTATE] = {C0.x,C0.y,C0.z,C0.w, C1.x,C1.y,C1.z,C1.w,
                          C2.x,C2.y,C2.z,C2.w, C3.x,C3.y,C3.z,C3.w};
      float u = u4[q], du = dt*u;
      float y = 0.f;
      if (geo){
        float w1 = EXP2F(dt * A2[0]);
        float wacc = 1.f;
#pragma unroll
        for (int n=0;n<NSTATE;n++){
          wacc *= w1;
          h[n] = h[n]*wacc + du * Bf[n];
          y = __builtin_fmaf(h[n], Cf[n], y);
        }
      } else {
#pragma unroll
        for (int n=0;n<NSTATE;n++){
          float w = EXP2F(dt * A2[n]);
          h[n] = h[n]*w + du * Bf[n];
          y = __builtin_fmaf(h[n], Cf[n], y);
        }
      }
      int tok = perm_tok(dir, t0 + tg + q);
      atomicAdd(ab + (size_t)tok*DINNER, y + u*Dd);
    }
  }
}

// acc *= silu(z); also emit bf16 (z read from bf16 xz)
__global__ void combine_k(float* __restrict__ acc, const short* __restrict__ xzb,
                          short* __restrict__ acc_b)
{
  int id = blockIdx.x*256 + threadIdx.x;     // < MROWS*DINNER
  int row = id / DINNER;
  int d = id - row*DINNER;
  float z = bs2f(xzb[(size_t)row*1536 + DINNER + d]);
  float v = acc[id] * silu_f(z);
  acc[id] = v;
  acc_b[id] = f2bs(v);
}

// layernorm over 384; fp32 out + bf16 out
__launch_bounds__(256)
__global__ void ln384_k(const float* __restrict__ in, float* __restrict__ out,
                        const float* __restrict__ w, const float* __restrict__ b,
                        short* __restrict__ bout)
{
  int wv = threadIdx.x >> 6, lane = threadIdx.x & 63;
  size_t row = (size_t)blockIdx.x * 4 + wv;
  const float* ip = in + row * DMODEL;
  float v[6];
#pragma unroll
  for (int k=0;k<6;k++) v[k] = ip[lane + 64*k];
  float s = 0.f;
#pragma unroll
  for (int k=0;k<6;k++) s += v[k];
#pragma unroll
  for (int o=32;o>0;o>>=1) s += __shfl_xor(s, o);
  float mu = s * (1.f/DMODEL);
  float ss = 0.f;
#pragma unroll
  for (int k=0;k<6;k++){ float dd = v[k]-mu; ss += dd*dd; }
#pragma unroll
  for (int o=32;o>0;o>>=1) ss += __shfl_xor(ss, o);
  float inv = rsqrtf(ss*(1.f/DMODEL) + 1e-5f);
  float* op = out + row * DMODEL;
  short* bp = bout + row * DMODEL;
#pragma unroll
  for (int k=0;k<6;k++){
    int c = lane + 64*k;
    float r = (v[k]-mu)*inv*w[c] + b[c];
    op[c] = r;
    bp[c] = f2bs(r);
  }
}

// pixel-shuffle gather + layernorm over 192 + fp32 store
__launch_bounds__(256)
__global__ void peln_k(const float* __restrict__ xe, const float* __restrict__ w,
                       const float* __restrict__ b, float* __restrict__ out)
{
  int wv = threadIdx.x >> 6, lane = threadIdx.x & 63;
  int row = blockIdx.x * 4 + wv;          // b*4096 + h2*64 + w2
  int bb = row >> 12;
  int r2 = row & 4095;
  int h2 = r2 >> 6, w2 = r2 & 63;
  int h = h2 >> 1, s1 = h2 & 1, w_ = w2 >> 1, s2 = w2 & 1;
  const float* ip = xe + ((size_t)(bb*1024 + h*32 + w_))*768 + (s1*2+s2)*192;
  float v[3];
#pragma unroll
  for (int k=0;k<3;k++) v[k] = ip[lane + 64*k];
  float s = v[0]+v[1]+v[2];
#pragma unroll
  for (int o=32;o>0;o>>=1) s += __shfl_xor(s, o);
  float mu = s * (1.f/192);
  float ss = 0.f;
#pragma unroll
  for (int k=0;k<3;k++){ float dd=v[k]-mu; ss+=dd*dd; }
#pragma unroll
  for (int o=32;o>0;o>>=1) ss += __shfl_xor(ss, o);
  float inv = rsqrtf(ss*(1.f/192) + 1e-5f);
  float* op = out + (size_t)row * 192;
#pragma unroll
  for (int k=0;k<3;k++){ int c = lane + 64*k; op[c] = (v[k]-mu)*inv*w[c] + b[c]; }
}

extern "C" void kernel_launch(void* const* d_in, const int* in_sizes, int n_in,
                              void* d_out, int out_size, void* d_ws, size_t ws_size,
                              hipStream_t stream)
{
  const float* x_in   = (const float*)d_in[0];
  const float* in_w   = (const float*)d_in[1];
  const float* conv_w = (const float*)d_in[2];
  const float* conv_b = (const float*)d_in[3];
  const float* xp_w   = (const float*)d_in[4];
  const float* dt_w   = (const float*)d_in[5];
  const float* dt_b   = (const float*)d_in[6];
  const float* A_log  = (const float*)d_in[7];
  const float* Dp     = (const float*)d_in[8];
  const float* mn_w   = (const float*)d_in[9];
  const float* mn_b   = (const float*)d_in[10];
  const float* mout_w = (const float*)d_in[11];
  const float* bp_w   = (const float*)d_in[12];
  const float* bp_b   = (const float*)d_in[13];
  const float* ln_w   = (const float*)d_in[14];
  const float* ln_b   = (const float*)d_in[15];
  const float* exp_w  = (const float*)d_in[16];
  const float* pe_w   = (const float*)d_in[17];
  const float* pe_b   = (const float*)d_in[18];

  float* ws = (float*)d_ws;
  // layout in float units
  float* xcur = ws;                                      // 1,572,864
  short* xz_b = (short*)(xcur + 1572864);                // 6,291,456 shorts
  short* ucv_b = (short*)(xcur + 1572864 + 3145728);     // 12,582,912 shorts
  float* xdb  = xcur + 1572864 + 3145728 + 6291456;      // 917,504
  float* scratch = xdb + 917504;                         // 12,582,912 (t3|t2b|acc_b)
  float* acc  = scratch + 12582912;                      // 3,145,728
  float* big  = acc + 3145728;                           // 6,291,456 (t1|t2 or hLb)
  float* t1   = big;
  float* t2   = t1 + 1572864;
  float* hLb  = big;
  short* in_w_b   = (short*)(big + 6291456);
  short* xp_w_b   = in_w_b + (size_t)2*1536*DMODEL;
  short* mout_w_b = xp_w_b + (size_t)2*GCOLS*DINNER;
  short* bp_w_b   = mout_w_b + (size_t)2*DMODEL*DINNER;
  short* exp_w_b  = bp_w_b + (size_t)2*DMODEL*DMODEL;
  float* sums     = (float*)(exp_w_b + (size_t)2*DMODEL*DMODEL);  // 393,216 f
  short* xcur_b   = (short*)(sums + 393216);             // 3,145,728 sh
  // aliases inside scratch
  float* t3    = scratch;
  short* t2b   = (short*)(scratch + (size_t)2*1024*1024);
  short* acc_b = (short*)(scratch + (size_t)3*1024*1024 + 262144);
  float* xe    = acc;

  // weight conversions (single batched launch)
  {
    int s0 = 2*1536*DMODEL, s1 = 2*GCOLS*DINNER, s2 = 2*DMODEL*DINNER,
        s3 = 2*DMODEL*DMODEL, s4 = 2*DMODEL*DMODEL;
    int tot = s0+s1+s2+s3+s4;
    f2b5_k<<<dim3((tot+255)/256), dim3(256), 0, stream>>>(
        in_w, xp_w, mout_w, bp_w, exp_w, in_w_b, s0, s1, s2, s3, s4);
  }
  cvt_dual_k<<<dim3((MROWS*DMODEL)/256), dim3(256), 0, stream>>>(x_in, xcur, xcur_b, MROWS*DMODEL);

  for (int i = 0; i < 2; i++) {
    // xz_b = bf16( x @ in_w^T )  (M=4096, N=1536, K=384)  [MFMA, bf16 out]
    gemm_mfma_bout_k<<<dim3(24,64), dim3(256), 0, stream>>>(
        xcur_b, DMODEL, in_w_b + (size_t)i*1536*DMODEL, DMODEL,
        xz_b, 1536, 1536, DMODEL);

    // depthwise conv + silu (bf16 in/out)
    conv_k<<<dim3((4*MROWS*DINNER)/256), dim3(256), 0, stream>>>(
        xz_b, conv_w + (size_t)i*DINNER*4, conv_b + (size_t)i*DINNER, ucv_b);

    // xdb = u @ xp_w^T  (M=16384, N=56, K=768)  [MFMA, merged dirs]
    gemm_mfma_k<0><<<dim3(1,256), dim3(256), 0, stream>>>(
        ucv_b, DINNER, xp_w_b + (size_t)i*GCOLS*DINNER, DINNER,
        xdb, GCOLS, GCOLS, DINNER, nullptr, nullptr);

    hipMemsetAsync(acc, 0, (size_t)MROWS*DINNER*sizeof(float), stream);
    chunk_scan_k<<<dim3(3, NCHUNK, 16), dim3(256), 0, stream>>>(
        ucv_b, xdb, A_log + (size_t)i*DINNER*NSTATE,
        dt_w + (size_t)i*DINNER*DTRANK, dt_b + (size_t)i*DINNER, sums, hLb);
    chunk_comb_k<<<dim3(48), dim3(256), 0, stream>>>(sums, A_log + (size_t)i*DINNER*NSTATE, hLb);
    chunk_emit_k<<<dim3(3, NCHUNK, 16), dim3(256), 0, stream>>>(
        ucv_b, xdb, A_log + (size_t)i*DINNER*NSTATE,
        dt_w + (size_t)i*DINNER*DTRANK, dt_b + (size_t)i*DINNER,
        Dp + (size_t)i*DINNER, hLb, acc);
    combine_k<<<dim3((MROWS*DINNER)/256), dim3(256), 0, stream>>>(acc, xz_b, acc_b);

    // t1 = ymix @ mout_w^T  (N=384, K=768)  [MFMA]
    gemm_mfma_k<0><<<dim3(6,64), dim3(256), 0, stream>>>(
        acc_b, DINNER, mout_w_b + (size_t)i*DMODEL*DINNER, DINNER,
        t1, DMODEL, DMODEL, DINNER, nullptr, nullptr);
    ln384_k<<<dim3(1024), dim3(256), 0, stream>>>(t1, t2, mn_w + (size_t)i*DMODEL, mn_b + (size_t)i*DMODEL, t2b);
    // t3 = xcur + t2 @ bp_w^T + bp_b  (N=384, K=384)  [MFMA + bias + res]
    gemm_mfma_k<2><<<dim3(6,64), dim3(256), 0, stream>>>(
        t2b, DMODEL, bp_w_b + (size_t)i*DMODEL*DMODEL, DMODEL,
        t3, DMODEL, DMODEL, DMODEL, bp_b + (size_t)i*DMODEL, xcur);
    ln384_k<<<dim3(1024), dim3(256), 0, stream>>>(t3, xcur, ln_w + (size_t)i*DMODEL, ln_b + (size_t)i*DMODEL, xcur_b);
  }

  // xe = x @ exp_w^T  (M=4096, N=768, K=384)  [MFMA]
  gemm_mfma_k<0><<<dim3(12,64), dim3(256), 0, stream>>>(
      xcur_b, DMODEL, exp_w_b, DMODEL, xe, 2*DMODEL, 2*DMODEL, DMODEL, nullptr, nullptr);
  // pixel-shuffle + LN(192) -> fp32 out
  peln_k<<<dim3(4096), dim3(256), 0, stream>>>(xe, pe_w, pe_b, (float*)d_out);
}

// Round 11
// 775.644 us; speedup vs baseline: 1.0572x; 1.0572x over previous
//
#include <hip/hip_runtime.h>
#include <hip/hip_bf16.h>
#include <math.h>

typedef __hip_bfloat16 bf16;

#define MROWS 4096      // BATCH * L
#define DMODEL 384
#define DINNER 768
#define GCOLS 56        // DT_RANK + 2*D_STATE
#define DTRANK 24
#define NSTATE 16
#define NCHUNK 32
#define TCHUNK 32

typedef __attribute__((ext_vector_type(8))) short bf16x8;
typedef __attribute__((ext_vector_type(4))) float f32x4;

#if __has_builtin(__builtin_amdgcn_exp2f)
#define EXP2F(x) __builtin_amdgcn_exp2f(x)
#else
#define EXP2F(x) exp2f(x)
#endif

__device__ __forceinline__ float silu_f(float x){ return x / (1.f + __expf(-x)); }
__device__ __forceinline__ float softplus_f(float x){
  return (x > 20.f) ? x : __logf(1.f + __expf(x));
}
__device__ __forceinline__ short f2bs(float x){
  bf16 h = __float2bfloat16(x);
  return *(short*)&h;
}
__device__ __forceinline__ float bs2f(short s){
  bf16 h = *(bf16*)&s;
  return __bfloat162float(h);
}

// seq index t -> token index, per direction
__device__ __forceinline__ int perm_tok(int dir, int t){
  if (dir == 0) return t;
  if (dir == 2) return 1023 - t;
  int tt = (dir == 1) ? t : (1023 - t);
  int i = tt >> 5, j = tt & 31;
  return ((31 - j) << 5) | i;   // token = (31-j)*32 + i
}

// ---------------- bf16 MFMA GEMM: C[M,N] = A[M,K] @ W[N,K]^T (fp32 accum) ----
// EPI 0: none (fp32 out); 2: + bias[n] + res[m,n] (fp32 out)
template<int EPI>
__launch_bounds__(256)
__global__ void gemm_mfma_k(const short* __restrict__ A, int lda,
                            const short* __restrict__ W, int ldw,
                            float* __restrict__ C, int ldc,
                            int Ndim, int Kdim,
                            const float* __restrict__ bias,
                            const float* __restrict__ res)
{
  const int wv = threadIdx.x >> 6, lane = threadIdx.x & 63;
  const int m0 = blockIdx.y * 64;
  const int n0 = blockIdx.x * 64 + wv * 16;
  const int lm = lane & 15;          // fragment row (A-m / B-n)
  const int kq = (lane >> 4) * 8;    // fragment k offset
  f32x4 acc0 = {0.f,0.f,0.f,0.f}, acc1 = acc0, acc2 = acc0, acc3 = acc0;
  const bool nok = (n0 + lm) < Ndim;
  const short* ap = A + (size_t)(m0 + lm) * lda + kq;
  const short* wp = W + (size_t)(nok ? (n0 + lm) : 0) * ldw + kq;
  const size_t ar16 = (size_t)16 * lda;
  const bf16x8 bz = {0,0,0,0,0,0,0,0};

  for (int k0 = 0; k0 < Kdim; k0 += 32) {
    bf16x8 b = bz;
    if (nok) b = *(const bf16x8*)(wp + k0);
    bf16x8 a0 = *(const bf16x8*)(ap + k0);
    bf16x8 a1 = *(const bf16x8*)(ap + ar16 + k0);
    bf16x8 a2 = *(const bf16x8*)(ap + 2*ar16 + k0);
    bf16x8 a3 = *(const bf16x8*)(ap + 3*ar16 + k0);
    acc0 = __builtin_amdgcn_mfma_f32_16x16x32_bf16(a0, b, acc0, 0, 0, 0);
    acc1 = __builtin_amdgcn_mfma_f32_16x16x32_bf16(a1, b, acc1, 0, 0, 0);
    acc2 = __builtin_amdgcn_mfma_f32_16x16x32_bf16(a2, b, acc2, 0, 0, 0);
    acc3 = __builtin_amdgcn_mfma_f32_16x16x32_bf16(a3, b, acc3, 0, 0, 0);
  }

  const int ncol = n0 + lm;                 // C/D: col = lane&15
  if (ncol < Ndim) {
    const int mr = m0 + (lane >> 4) * 4;    // C/D: row = quad*4 + reg
    f32x4 av[4] = {acc0, acc1, acc2, acc3};
#pragma unroll
    for (int mt = 0; mt < 4; mt++) {
#pragma unroll
      for (int reg = 0; reg < 4; reg++) {
        int m = mr + mt*16 + reg;
        float v = av[mt][reg];
        if (EPI == 2) v += bias[ncol] + res[(size_t)m*ldc + ncol];
        C[(size_t)m*ldc + ncol] = v;
      }
    }
  }
}

// same GEMM but bf16 output (for in_proj -> xz_b)
__launch_bounds__(256)
__global__ void gemm_mfma_bout_k(const short* __restrict__ A, int lda,
                                 const short* __restrict__ W, int ldw,
                                 short* __restrict__ C, int ldc,
                                 int Ndim, int Kdim)
{
  const int wv = threadIdx.x >> 6, lane = threadIdx.x & 63;
  const int m0 = blockIdx.y * 64;
  const int n0 = blockIdx.x * 64 + wv * 16;
  const int lm = lane & 15;
  const int kq = (lane >> 4) * 8;
  f32x4 acc0 = {0.f,0.f,0.f,0.f}, acc1 = acc0, acc2 = acc0, acc3 = acc0;
  const bool nok = (n0 + lm) < Ndim;
  const short* ap = A + (size_t)(m0 + lm) * lda + kq;
  const short* wp = W + (size_t)(nok ? (n0 + lm) : 0) * ldw + kq;
  const size_t ar16 = (size_t)16 * lda;
  const bf16x8 bz = {0,0,0,0,0,0,0,0};

  for (int k0 = 0; k0 < Kdim; k0 += 32) {
    bf16x8 b = bz;
    if (nok) b = *(const bf16x8*)(wp + k0);
    bf16x8 a0 = *(const bf16x8*)(ap + k0);
    bf16x8 a1 = *(const bf16x8*)(ap + ar16 + k0);
    bf16x8 a2 = *(const bf16x8*)(ap + 2*ar16 + k0);
    bf16x8 a3 = *(const bf16x8*)(ap + 3*ar16 + k0);
    acc0 = __builtin_amdgcn_mfma_f32_16x16x32_bf16(a0, b, acc0, 0, 0, 0);
    acc1 = __builtin_amdgcn_mfma_f32_16x16x32_bf16(a1, b, acc1, 0, 0, 0);
    acc2 = __builtin_amdgcn_mfma_f32_16x16x32_bf16(a2, b, acc2, 0, 0, 0);
    acc3 = __builtin_amdgcn_mfma_f32_16x16x32_bf16(a3, b, acc3, 0, 0, 0);
  }

  const int ncol = n0 + lm;
  if (ncol < Ndim) {
    const int mr = m0 + (lane >> 4) * 4;
    f32x4 av[4] = {acc0, acc1, acc2, acc3};
#pragma unroll
    for (int mt = 0; mt < 4; mt++) {
#pragma unroll
      for (int reg = 0; reg < 4; reg++) {
        int m = mr + mt*16 + reg;
        C[(size_t)m*ldc + ncol] = f2bs(av[mt][reg]);
      }
    }
  }
}

// ---------------- conversions / misc ----------------
__global__ void f2b5_k(const float* __restrict__ a0, const float* __restrict__ a1,
                       const float* __restrict__ a2, const float* __restrict__ a3,
                       const float* __restrict__ a4, short* __restrict__ o,
                       int s0, int s1, int s2, int s3, int s4)
{
  int id = blockIdx.x*256 + threadIdx.x;
  int e0 = s0, e1 = e0+s1, e2 = e1+s2, e3 = e2+s3, e4 = e3+s4;
  if (id >= e4) return;
  float v;
  if      (id < e0) v = a0[id];
  else if (id < e1) v = a1[id-e0];
  else if (id < e2) v = a2[id-e1];
  else if (id < e3) v = a3[id-e2];
  else              v = a4[id-e3];
  o[id] = f2bs(v);
}
__global__ void cvt_dual_k(const float* __restrict__ in, float* __restrict__ of,
                           short* __restrict__ ob, int n){
  int id = blockIdx.x*256 + threadIdx.x;
  if (id < n) { float v = in[id]; of[id] = v; ob[id] = f2bs(v); }
}

// depthwise causal conv (k=4) over permuted sequence + bias + silu; bf16 in/out
__launch_bounds__(256)
__global__ void conv_k(const short* __restrict__ xzb, const float* __restrict__ cw,
                       const float* __restrict__ cb, short* __restrict__ ucv_b)
{
  int id = blockIdx.x*256 + threadIdx.x;          // ((dir*4+b)*1024+t)*768+d
  int d = id % DINNER;
  int t = (id / DINNER) & 1023;
  int btdir = id / (DINNER*1024);
  int b_ = btdir & 3, dir = btdir >> 2;
  float s = cb[d];
  const short* up = xzb + (size_t)b_*1024*1536 + d;
#pragma unroll
  for (int j=0;j<4;j++){
    int tm = t - 3 + j;
    if (tm >= 0) s += cw[d*4+j] * bs2f(up[(size_t)perm_tok(dir,tm)*1536]);
  }
  ucv_b[id] = f2bs(silu_f(s));
}

// ============ chunked selective scan (dt fused in pass A, cached for pass C) ============
// Pass A: grid (3, NCHUNK, 16): local scan from 0 -> hL[n]; store dt (fp32) + sum_dt
__launch_bounds__(256)
__global__ void chunk_scan_k(const short* __restrict__ ucv_b,
                             const float* __restrict__ xdb, const float* __restrict__ A_log,
                             const float* __restrict__ dt_w, const float* __restrict__ dt_b,
                             float* __restrict__ dt_sv,
                             float* __restrict__ sums, float* __restrict__ hLb)
{
  const int d  = blockIdx.x * 256 + threadIdx.x;   // 0..767
  const int c  = blockIdx.y;                       // chunk
  const int bd = blockIdx.z;                       // dir*4+b

  float A2[NSTATE];
#pragma unroll
  for (int n=0;n<NSTATE;n++)
    A2[n] = -__expf(A_log[d*NSTATE + n]) * 1.44269504f;
  float w24[DTRANK];
#pragma unroll
  for (int r=0;r<DTRANK;r++) w24[r] = dt_w[d*DTRANK + r];
  const float bias = dt_b[d];

  const size_t rowbase = (size_t)bd*1024 + (size_t)c*TCHUNK;
  const short* up  = ucv_b + rowbase*DINNER + d;
  const float* bc  = xdb + rowbase*GCOLS;            // block-uniform
  float* dtp = dt_sv + rowbase*DINNER + d;

  float h[NSTATE] = {};
  float sdt = 0.f;

  for (int tg=0; tg<TCHUNK; tg+=4){
    float u4[4];
#pragma unroll
    for (int q=0;q<4;q++)
      u4[q]  = bs2f(up[(size_t)(tg+q)*DINNER]);
#pragma unroll
    for (int q=0;q<4;q++){
      const float* Xr = bc + (tg+q)*GCOLS;           // uniform -> s_load
      float v = bias;
#pragma unroll
      for (int r=0;r<DTRANK;r++) v = __builtin_fmaf(Xr[r], w24[r], v);
      float dt = softplus_f(v);
      dtp[(size_t)(tg+q)*DINNER] = dt;
      const float* Bv = Xr + DTRANK;
      float4 B0 = *(const float4*)(Bv+0), B1 = *(const float4*)(Bv+4);
      float4 B2 = *(const float4*)(Bv+8), B3 = *(const float4*)(Bv+12);
      float Bf[NSTATE] = {B0.x,B0.y,B0.z,B0.w, B1.x,B1.y,B1.z,B1.w,
                          B2.x,B2.y,B2.z,B2.w, B3.x,B3.y,B3.z,B3.w};
      float du = dt*u4[q];
      sdt += dt;
#pragma unroll
      for (int n=0;n<NSTATE;n++){
        float w = EXP2F(dt * A2[n]);
        h[n] = h[n]*w + du * Bf[n];
      }
    }
  }
  size_t ob = ((size_t)(bd*NCHUNK + c) * NSTATE) * DINNER + d;
#pragma unroll
  for (int n=0;n<NSTATE;n++)
    hLb[ob + (size_t)n*DINNER] = h[n];
  sums[(size_t)(bd*NCHUNK + c)*DINNER + d] = sdt;
}

// Pass B: serial combine over chunks; W reconstructed from sum_dt; hLb -> chunk-initial h0
__launch_bounds__(256)
__global__ void chunk_comb_k(const float* __restrict__ sums, const float* __restrict__ A_log,
                             float* __restrict__ hLb)
{
  int id = blockIdx.x*256 + threadIdx.x;    // (dir*4+b)*768+d
  int d = id % DINNER;
  int bd = id / DINNER;
  float A2[NSTATE];
#pragma unroll
  for (int n=0;n<NSTATE;n++)
    A2[n] = -__expf(A_log[d*NSTATE + n]) * 1.44269504f;
  float h[NSTATE] = {};
  for (int c=0; c<NCHUNK; c++){
    size_t ob = ((size_t)(bd*NCHUNK + c) * NSTATE) * DINNER + d;
    float sdt = sums[(size_t)(bd*NCHUNK + c)*DINNER + d];
#pragma unroll
    for (int n=0;n<NSTATE;n++){
      float Wc = EXP2F(A2[n] * sdt);
      float hL = hLb[ob + (size_t)n*DINNER];
      float h0 = h[n];
      h[n] = Wc*h0 + hL;
      hLb[ob + (size_t)n*DINNER] = h0;
    }
  }
}

// Pass C: replay from h0 using cached dt, emit y, scatter-add token-space
__launch_bounds__(256)
__global__ void chunk_emit_k(const short* __restrict__ ucv_b,
                             const float* __restrict__ xdb, const float* __restrict__ A_log,
                             const float* __restrict__ dt_sv,
                             const float* __restrict__ Dp, const float* __restrict__ h0b,
                             float* __restrict__ acc)
{
  const int d  = blockIdx.x * 256 + threadIdx.x;
  const int c  = blockIdx.y;
  const int bd = blockIdx.z;
  const int b  = bd & 3, dir = bd >> 2;

  float A2[NSTATE];
#pragma unroll
  for (int n=0;n<NSTATE;n++)
    A2[n] = -__expf(A_log[d*NSTATE + n]) * 1.44269504f;
  float Dd = Dp[d];

  const size_t rowbase = (size_t)bd*1024 + (size_t)c*TCHUNK;
  const short* up  = ucv_b + rowbase*DINNER + d;
  const float* bc  = xdb + rowbase*GCOLS;            // block-uniform
  const float* dtp = dt_sv + rowbase*DINNER + d;
  float* ab = acc + (size_t)b*1024*DINNER + d;

  float h[NSTATE];
  size_t ob = ((size_t)(bd*NCHUNK + c) * NSTATE) * DINNER + d;
#pragma unroll
  for (int n=0;n<NSTATE;n++) h[n] = h0b[ob + (size_t)n*DINNER];

  const int t0 = c * TCHUNK;
  for (int tg=0; tg<TCHUNK; tg+=4){
    float u4[4], dt4[4];
#pragma unroll
    for (int q=0;q<4;q++){
      u4[q]  = bs2f(up[(size_t)(tg+q)*DINNER]);
      dt4[q] = dtp[(size_t)(tg+q)*DINNER];
    }
#pragma unroll
    for (int q=0;q<4;q++){
      const float* Bv = bc + (tg+q)*GCOLS + DTRANK;  // uniform -> s_load
      float4 B0 = *(const float4*)(Bv+0), B1 = *(const float4*)(Bv+4);
      float4 B2 = *(const float4*)(Bv+8), B3 = *(const float4*)(Bv+12);
      float4 C0 = *(const float4*)(Bv+16), C1 = *(const float4*)(Bv+20);
      float4 C2 = *(const float4*)(Bv+24), C3 = *(const float4*)(Bv+28);
      float Bf[NSTATE] = {B0.x,B0.y,B0.z,B0.w, B1.x,B1.y,B1.z,B1.w,
                          B2.x,B2.y,B2.z,B2.w, B3.x,B3.y,B3.z,B3.w};
      float Cf[NSTATE] = {C0.x,C0.y,C0.z,C0.w, C1.x,C1.y,C1.z,C1.w,
                          C2.x,C2.y,C2.z,C2.w, C3.x,C3.y,C3.z,C3.w};
      float dt = dt4[q], u = u4[q], du = dt*u;
      float y = 0.f;
#pragma unroll
      for (int n=0;n<NSTATE;n++){
        float w = EXP2F(dt * A2[n]);
        h[n] = h[n]*w + du * Bf[n];
        y = __builtin_fmaf(h[n], Cf[n], y);
      }
      int tok = perm_tok(dir, t0 + tg + q);
      atomicAdd(ab + (size_t)tok*DINNER, y + u*Dd);
    }
  }
}

// acc *= silu(z); also emit bf16 (z read from bf16 xz)
__global__ void combine_k(float* __restrict__ acc, const short* __restrict__ xzb,
                          short* __restrict__ acc_b)
{
  int id = blockIdx.x*256 + threadIdx.x;     // < MROWS*DINNER
  int row = id / DINNER;
  int d = id - row*DINNER;
  float z = bs2f(xzb[(size_t)row*1536 + DINNER + d]);
  float v = acc[id] * silu_f(z);
  acc[id] = v;
  acc_b[id] = f2bs(v);
}

// layernorm over 384; fp32 out + bf16 out
__launch_bounds__(256)
__global__ void ln384_k(const float* __restrict__ in, float* __restrict__ out,
                        const float* __restrict__ w, const float* __restrict__ b,
                        short* __restrict__ bout)
{
  int wv = threadIdx.x >> 6, lane = threadIdx.x & 63;
  size_t row = (size_t)blockIdx.x * 4 + wv;
  const float* ip = in + row * DMODEL;
  float v[6];
#pragma unroll
  for (int k=0;k<6;k++) v[k] = ip[lane + 64*k];
  float s = 0.f;
#pragma unroll
  for (int k=0;k<6;k++) s += v[k];
#pragma unroll
  for (int o=32;o>0;o>>=1) s += __shfl_xor(s, o);
  float mu = s * (1.f/DMODEL);
  float ss = 0.f;
#pragma unroll
  for (int k=0;k<6;k++){ float dd = v[k]-mu; ss += dd*dd; }
#pragma unroll
  for (int o=32;o>0;o>>=1) ss += __shfl_xor(ss, o);
  float inv = rsqrtf(ss*(1.f/DMODEL) + 1e-5f);
  float* op = out + row * DMODEL;
  short* bp = bout + row * DMODEL;
#pragma unroll
  for (int k=0;k<6;k++){
    int c = lane + 64*k;
    float r = (v[k]-mu)*inv*w[c] + b[c];
    op[c] = r;
    bp[c] = f2bs(r);
  }
}

// pixel-shuffle gather + layernorm over 192 + fp32 store
__launch_bounds__(256)
__global__ void peln_k(const float* __restrict__ xe, const float* __restrict__ w,
                       const float* __restrict__ b, float* __restrict__ out)
{
  int wv = threadIdx.x >> 6, lane = threadIdx.x & 63;
  int row = blockIdx.x * 4 + wv;          // b*4096 + h2*64 + w2
  int bb = row >> 12;
  int r2 = row & 4095;
  int h2 = r2 >> 6, w2 = r2 & 63;
  int h = h2 >> 1, s1 = h2 & 1, w_ = w2 >> 1, s2 = w2 & 1;
  const float* ip = xe + ((size_t)(bb*1024 + h*32 + w_))*768 + (s1*2+s2)*192;
  float v[3];
#pragma unroll
  for (int k=0;k<3;k++) v[k] = ip[lane + 64*k];
  float s = v[0]+v[1]+v[2];
#pragma unroll
  for (int o=32;o>0;o>>=1) s += __shfl_xor(s, o);
  float mu = s * (1.f/192);
  float ss = 0.f;
#pragma unroll
  for (int k=0;k<3;k++){ float dd=v[k]-mu; ss+=dd*dd; }
#pragma unroll
  for (int o=32;o>0;o>>=1) ss += __shfl_xor(ss, o);
  float inv = rsqrtf(ss*(1.f/192) + 1e-5f);
  float* op = out + (size_t)row * 192;
#pragma unroll
  for (int k=0;k<3;k++){ int c = lane + 64*k; op[c] = (v[k]-mu)*inv*w[c] + b[c]; }
}

extern "C" void kernel_launch(void* const* d_in, const int* in_sizes, int n_in,
                              void* d_out, int out_size, void* d_ws, size_t ws_size,
                              hipStream_t stream)
{
  const float* x_in   = (const float*)d_in[0];
  const float* in_w   = (const float*)d_in[1];
  const float* conv_w = (const float*)d_in[2];
  const float* conv_b = (const float*)d_in[3];
  const float* xp_w   = (const float*)d_in[4];
  const float* dt_w   = (const float*)d_in[5];
  const float* dt_b   = (const float*)d_in[6];
  const float* A_log  = (const float*)d_in[7];
  const float* Dp     = (const float*)d_in[8];
  const float* mn_w   = (const float*)d_in[9];
  const float* mn_b   = (const float*)d_in[10];
  const float* mout_w = (const float*)d_in[11];
  const float* bp_w   = (const float*)d_in[12];
  const float* bp_b   = (const float*)d_in[13];
  const float* ln_w   = (const float*)d_in[14];
  const float* ln_b   = (const float*)d_in[15];
  const float* exp_w  = (const float*)d_in[16];
  const float* pe_w   = (const float*)d_in[17];
  const float* pe_b   = (const float*)d_in[18];

  float* ws = (float*)d_ws;
  // layout in float units
  float* xcur = ws;                                      // 1,572,864
  short* xz_b = (short*)(xcur + 1572864);                // 6,291,456 shorts
  short* ucv_b = (short*)(xcur + 1572864 + 3145728);     // 12,582,912 shorts
  float* xdb  = xcur + 1572864 + 3145728 + 6291456;      // 917,504
  float* scratch = xdb + 917504;                         // 12,582,912 (dt_sv | t3|t2b|acc_b)
  float* acc  = scratch + 12582912;                      // 3,145,728
  float* big  = acc + 3145728;                           // 6,291,456 (t1|t2 or hLb)
  float* t1   = big;
  float* t2   = t1 + 1572864;
  float* hLb  = big;
  short* in_w_b   = (short*)(big + 6291456);
  short* xp_w_b   = in_w_b + (size_t)2*1536*DMODEL;
  short* mout_w_b = xp_w_b + (size_t)2*GCOLS*DINNER;
  short* bp_w_b   = mout_w_b + (size_t)2*DMODEL*DINNER;
  short* exp_w_b  = bp_w_b + (size_t)2*DMODEL*DMODEL;
  float* sums     = (float*)(exp_w_b + (size_t)2*DMODEL*DMODEL);  // 393,216 f
  short* xcur_b   = (short*)(sums + 393216);             // 3,145,728 sh
  // aliases inside scratch (scan phase: dt_sv; post-scan: t3/t2b/acc_b)
  float* dt_sv = scratch;                                // 16384*768 = 12,582,912 f exactly
  float* t3    = scratch;
  short* t2b   = (short*)(scratch + (size_t)2*1024*1024);
  short* acc_b = (short*)(scratch + (size_t)3*1024*1024 + 262144);
  float* xe    = acc;

  // weight conversions (single batched launch)
  {
    int s0 = 2*1536*DMODEL, s1 = 2*GCOLS*DINNER, s2 = 2*DMODEL*DINNER,
        s3 = 2*DMODEL*DMODEL, s4 = 2*DMODEL*DMODEL;
    int tot = s0+s1+s2+s3+s4;
    f2b5_k<<<dim3((tot+255)/256), dim3(256), 0, stream>>>(
        in_w, xp_w, mout_w, bp_w, exp_w, in_w_b, s0, s1, s2, s3, s4);
  }
  cvt_dual_k<<<dim3((MROWS*DMODEL)/256), dim3(256), 0, stream>>>(x_in, xcur, xcur_b, MROWS*DMODEL);

  for (int i = 0; i < 2; i++) {
    // xz_b = bf16( x @ in_w^T )  (M=4096, N=1536, K=384)  [MFMA, bf16 out]
    gemm_mfma_bout_k<<<dim3(24,64), dim3(256), 0, stream>>>(
        xcur_b, DMODEL, in_w_b + (size_t)i*1536*DMODEL, DMODEL,
        xz_b, 1536, 1536, DMODEL);

    // depthwise conv + silu (bf16 in/out)
    conv_k<<<dim3((4*MROWS*DINNER)/256), dim3(256), 0, stream>>>(
        xz_b, conv_w + (size_t)i*DINNER*4, conv_b + (size_t)i*DINNER, ucv_b);

    // xdb = u @ xp_w^T  (M=16384, N=56, K=768)  [MFMA, merged dirs]
    gemm_mfma_k<0><<<dim3(1,256), dim3(256), 0, stream>>>(
        ucv_b, DINNER, xp_w_b + (size_t)i*GCOLS*DINNER, DINNER,
        xdb, GCOLS, GCOLS, DINNER, nullptr, nullptr);

    hipMemsetAsync(acc, 0, (size_t)MROWS*DINNER*sizeof(float), stream);
    chunk_scan_k<<<dim3(3, NCHUNK, 16), dim3(256), 0, stream>>>(
        ucv_b, xdb, A_log + (size_t)i*DINNER*NSTATE,
        dt_w + (size_t)i*DINNER*DTRANK, dt_b + (size_t)i*DINNER,
        dt_sv, sums, hLb);
    chunk_comb_k<<<dim3(48), dim3(256), 0, stream>>>(sums, A_log + (size_t)i*DINNER*NSTATE, hLb);
    chunk_emit_k<<<dim3(3, NCHUNK, 16), dim3(256), 0, stream>>>(
        ucv_b, xdb, A_log + (size_t)i*DINNER*NSTATE,
        dt_sv, Dp + (size_t)i*DINNER, hLb, acc);
    combine_k<<<dim3((MROWS*DINNER)/256), dim3(256), 0, stream>>>(acc, xz_b, acc_b);

    // t1 = ymix @ mout_w^T  (N=384, K=768)  [MFMA]
    gemm_mfma_k<0><<<dim3(6,64), dim3(256), 0, stream>>>(
        acc_b, DINNER, mout_w_b + (size_t)i*DMODEL*DINNER, DINNER,
        t1, DMODEL, DMODEL, DINNER, nullptr, nullptr);
    ln384_k<<<dim3(1024), dim3(256), 0, stream>>>(t1, t2, mn_w + (size_t)i*DMODEL, mn_b + (size_t)i*DMODEL, t2b);
    // t3 = xcur + t2 @ bp_w^T + bp_b  (N=384, K=384)  [MFMA + bias + res]
    gemm_mfma_k<2><<<dim3(6,64), dim3(256), 0, stream>>>(
        t2b, DMODEL, bp_w_b + (size_t)i*DMODEL*DMODEL, DMODEL,
        t3, DMODEL, DMODEL, DMODEL, bp_b + (size_t)i*DMODEL, xcur);
    ln384_k<<<dim3(1024), dim3(256), 0, stream>>>(t3, xcur, ln_w + (size_t)i*DMODEL, ln_b + (size_t)i*DMODEL, xcur_b);
  }

  // xe = x @ exp_w^T  (M=4096, N=768, K=384)  [MFMA]
  gemm_mfma_k<0><<<dim3(12,64), dim3(256), 0, stream>>>(
      xcur_b, DMODEL, exp_w_b, DMODEL, xe, 2*DMODEL, 2*DMODEL, DMODEL, nullptr, nullptr);
  // pixel-shuffle + LN(192) -> fp32 out
  peln_k<<<dim3(4096), dim3(256), 0, stream>>>(xe, pe_w, pe_b, (float*)d_out);
}

// Round 12
// 757.709 us; speedup vs baseline: 1.0822x; 1.0237x over previous
//
#include <hip/hip_runtime.h>
#include <hip/hip_bf16.h>
#include <math.h>

typedef __hip_bfloat16 bf16;

#define MROWS 4096      // BATCH * L
#define DMODEL 384
#define DINNER 768
#define GCOLS 56        // DT_RANK + 2*D_STATE
#define DTRANK 24
#define NSTATE 16
#define NCHUNK 32
#define TCHUNK 32

typedef __attribute__((ext_vector_type(8))) short bf16x8;
typedef __attribute__((ext_vector_type(4))) float f32x4;

#if __has_builtin(__builtin_amdgcn_exp2f)
#define EXP2F(x) __builtin_amdgcn_exp2f(x)
#else
#define EXP2F(x) exp2f(x)
#endif

__device__ __forceinline__ float silu_f(float x){ return x / (1.f + __expf(-x)); }
__device__ __forceinline__ float softplus_f(float x){
  return (x > 20.f) ? x : __logf(1.f + __expf(x));
}
__device__ __forceinline__ short f2bs(float x){
  bf16 h = __float2bfloat16(x);
  return *(short*)&h;
}
__device__ __forceinline__ float bs2f(short s){
  bf16 h = *(bf16*)&s;
  return __bfloat162float(h);
}

// seq index t -> token index, per direction
__device__ __forceinline__ int perm_tok(int dir, int t){
  if (dir == 0) return t;
  if (dir == 2) return 1023 - t;
  int tt = (dir == 1) ? t : (1023 - t);
  int i = tt >> 5, j = tt & 31;
  return ((31 - j) << 5) | i;   // token = (31-j)*32 + i
}

// ---------------- bf16 MFMA GEMM: C[M,N] = A[M,K] @ W[N,K]^T (fp32 accum) ----
// EPI 0: none (fp32 out); 2: + bias[n] + res[m,n] (fp32 out)
template<int EPI>
__launch_bounds__(256)
__global__ void gemm_mfma_k(const short* __restrict__ A, int lda,
                            const short* __restrict__ W, int ldw,
                            float* __restrict__ C, int ldc,
                            int Ndim, int Kdim,
                            const float* __restrict__ bias,
                            const float* __restrict__ res)
{
  const int wv = threadIdx.x >> 6, lane = threadIdx.x & 63;
  const int m0 = blockIdx.y * 64;
  const int n0 = blockIdx.x * 64 + wv * 16;
  const int lm = lane & 15;          // fragment row (A-m / B-n)
  const int kq = (lane >> 4) * 8;    // fragment k offset
  f32x4 acc0 = {0.f,0.f,0.f,0.f}, acc1 = acc0, acc2 = acc0, acc3 = acc0;
  const bool nok = (n0 + lm) < Ndim;
  const short* ap = A + (size_t)(m0 + lm) * lda + kq;
  const short* wp = W + (size_t)(nok ? (n0 + lm) : 0) * ldw + kq;
  const size_t ar16 = (size_t)16 * lda;
  const bf16x8 bz = {0,0,0,0,0,0,0,0};

  for (int k0 = 0; k0 < Kdim; k0 += 32) {
    bf16x8 b = bz;
    if (nok) b = *(const bf16x8*)(wp + k0);
    bf16x8 a0 = *(const bf16x8*)(ap + k0);
    bf16x8 a1 = *(const bf16x8*)(ap + ar16 + k0);
    bf16x8 a2 = *(const bf16x8*)(ap + 2*ar16 + k0);
    bf16x8 a3 = *(const bf16x8*)(ap + 3*ar16 + k0);
    acc0 = __builtin_amdgcn_mfma_f32_16x16x32_bf16(a0, b, acc0, 0, 0, 0);
    acc1 = __builtin_amdgcn_mfma_f32_16x16x32_bf16(a1, b, acc1, 0, 0, 0);
    acc2 = __builtin_amdgcn_mfma_f32_16x16x32_bf16(a2, b, acc2, 0, 0, 0);
    acc3 = __builtin_amdgcn_mfma_f32_16x16x32_bf16(a3, b, acc3, 0, 0, 0);
  }

  const int ncol = n0 + lm;                 // C/D: col = lane&15
  if (ncol < Ndim) {
    const int mr = m0 + (lane >> 4) * 4;    // C/D: row = quad*4 + reg
    f32x4 av[4] = {acc0, acc1, acc2, acc3};
#pragma unroll
    for (int mt = 0; mt < 4; mt++) {
#pragma unroll
      for (int reg = 0; reg < 4; reg++) {
        int m = mr + mt*16 + reg;
        float v = av[mt][reg];
        if (EPI == 2) v += bias[ncol] + res[(size_t)m*ldc + ncol];
        C[(size_t)m*ldc + ncol] = v;
      }
    }
  }
}

// same GEMM but bf16 output (for in_proj -> xz_b)
__launch_bounds__(256)
__global__ void gemm_mfma_bout_k(const short* __restrict__ A, int lda,
                                 const short* __restrict__ W, int ldw,
                                 short* __restrict__ C, int ldc,
                                 int Ndim, int Kdim)
{
  const int wv = threadIdx.x >> 6, lane = threadIdx.x & 63;
  const int m0 = blockIdx.y * 64;
  const int n0 = blockIdx.x * 64 + wv * 16;
  const int lm = lane & 15;
  const int kq = (lane >> 4) * 8;
  f32x4 acc0 = {0.f,0.f,0.f,0.f}, acc1 = acc0, acc2 = acc0, acc3 = acc0;
  const bool nok = (n0 + lm) < Ndim;
  const short* ap = A + (size_t)(m0 + lm) * lda + kq;
  const short* wp = W + (size_t)(nok ? (n0 + lm) : 0) * ldw + kq;
  const size_t ar16 = (size_t)16 * lda;
  const bf16x8 bz = {0,0,0,0,0,0,0,0};

  for (int k0 = 0; k0 < Kdim; k0 += 32) {
    bf16x8 b = bz;
    if (nok) b = *(const bf16x8*)(wp + k0);
    bf16x8 a0 = *(const bf16x8*)(ap + k0);
    bf16x8 a1 = *(const bf16x8*)(ap + ar16 + k0);
    bf16x8 a2 = *(const bf16x8*)(ap + 2*ar16 + k0);
    bf16x8 a3 = *(const bf16x8*)(ap + 3*ar16 + k0);
    acc0 = __builtin_amdgcn_mfma_f32_16x16x32_bf16(a0, b, acc0, 0, 0, 0);
    acc1 = __builtin_amdgcn_mfma_f32_16x16x32_bf16(a1, b, acc1, 0, 0, 0);
    acc2 = __builtin_amdgcn_mfma_f32_16x16x32_bf16(a2, b, acc2, 0, 0, 0);
    acc3 = __builtin_amdgcn_mfma_f32_16x16x32_bf16(a3, b, acc3, 0, 0, 0);
  }

  const int ncol = n0 + lm;
  if (ncol < Ndim) {
    const int mr = m0 + (lane >> 4) * 4;
    f32x4 av[4] = {acc0, acc1, acc2, acc3};
#pragma unroll
    for (int mt = 0; mt < 4; mt++) {
#pragma unroll
      for (int reg = 0; reg < 4; reg++) {
        int m = mr + mt*16 + reg;
        C[(size_t)m*ldc + ncol] = f2bs(av[mt][reg]);
      }
    }
  }
}

// ---------------- conversions / misc ----------------
__global__ void f2b5_k(const float* __restrict__ a0, const float* __restrict__ a1,
                       const float* __restrict__ a2, const float* __restrict__ a3,
                       const float* __restrict__ a4, short* __restrict__ o,
                       int s0, int s1, int s2, int s3, int s4)
{
  int id = blockIdx.x*256 + threadIdx.x;
  int e0 = s0, e1 = e0+s1, e2 = e1+s2, e3 = e2+s3, e4 = e3+s4;
  if (id >= e4) return;
  float v;
  if      (id < e0) v = a0[id];
  else if (id < e1) v = a1[id-e0];
  else if (id < e2) v = a2[id-e1];
  else if (id < e3) v = a3[id-e2];
  else              v = a4[id-e3];
  o[id] = f2bs(v);
}
__global__ void cvt_dual_k(const float* __restrict__ in, float* __restrict__ of,
                           short* __restrict__ ob, int n){
  int id = blockIdx.x*256 + threadIdx.x;
  if (id < n) { float v = in[id]; of[id] = v; ob[id] = f2bs(v); }
}

// depthwise causal conv (k=4) over permuted sequence + bias + silu; bf16 in/out
__launch_bounds__(256)
__global__ void conv_k(const short* __restrict__ xzb, const float* __restrict__ cw,
                       const float* __restrict__ cb, short* __restrict__ ucv_b)
{
  int id = blockIdx.x*256 + threadIdx.x;          // ((dir*4+b)*1024+t)*768+d
  int d = id % DINNER;
  int t = (id / DINNER) & 1023;
  int btdir = id / (DINNER*1024);
  int b_ = btdir & 3, dir = btdir >> 2;
  float s = cb[d];
  const short* up = xzb + (size_t)b_*1024*1536 + d;
#pragma unroll
  for (int j=0;j<4;j++){
    int tm = t - 3 + j;
    if (tm >= 0) s += cw[d*4+j] * bs2f(up[(size_t)perm_tok(dir,tm)*1536]);
  }
  ucv_b[id] = f2bs(silu_f(s));
}

// ============ chunked selective scan ============
// dt_k: grid (3, NCHUNK, 16): dt = softplus(xdb[:, :24] @ dt_w[d] + dt_b[d])
// one thread per d, TCHUNK rows; writes dt_sv + per-chunk sums
__launch_bounds__(256)
__global__ void dt_k(const float* __restrict__ xdb,
                     const float* __restrict__ dt_w, const float* __restrict__ dt_b,
                     float* __restrict__ dt_sv, float* __restrict__ sums)
{
  const int d  = blockIdx.x * 256 + threadIdx.x;   // 0..767
  const int c  = blockIdx.y;
  const int bd = blockIdx.z;

  float w24[DTRANK];
#pragma unroll
  for (int r=0;r<DTRANK;r++) w24[r] = dt_w[d*DTRANK + r];
  const float bias = dt_b[d];

  const size_t rowbase = (size_t)bd*1024 + (size_t)c*TCHUNK;
  const float* bc = xdb + rowbase*GCOLS;           // block-uniform
  float* dtp = dt_sv + rowbase*DINNER + d;

  float sdt = 0.f;
  for (int tt=0; tt<TCHUNK; tt++){
    const float* Xr = bc + tt*GCOLS;               // uniform -> s_load
    float v = bias;
#pragma unroll
    for (int r=0;r<DTRANK;r++) v = __builtin_fmaf(Xr[r], w24[r], v);
    float dt = softplus_f(v);
    dtp[(size_t)tt*DINNER] = dt;
    sdt += dt;
  }
  sums[(size_t)(bd*NCHUNK + c)*DINNER + d] = sdt;
}

// Pass A: grid (3, NCHUNK, 16): local scan from 0 -> hL[n], dt from cache
__launch_bounds__(256)
__global__ void chunk_scan_k(const short* __restrict__ ucv_b,
                             const float* __restrict__ xdb, const float* __restrict__ A_log,
                             const float* __restrict__ dt_sv,
                             float* __restrict__ hLb)
{
  const int d  = blockIdx.x * 256 + threadIdx.x;   // 0..767
  const int c  = blockIdx.y;                       // chunk
  const int bd = blockIdx.z;                       // dir*4+b

  float A2[NSTATE];
#pragma unroll
  for (int n=0;n<NSTATE;n++)
    A2[n] = -__expf(A_log[d*NSTATE + n]) * 1.44269504f;

  const size_t rowbase = (size_t)bd*1024 + (size_t)c*TCHUNK;
  const short* up  = ucv_b + rowbase*DINNER + d;
  const float* bc  = xdb + rowbase*GCOLS;            // block-uniform
  const float* dtp = dt_sv + rowbase*DINNER + d;

  float h[NSTATE] = {};

  for (int tg=0; tg<TCHUNK; tg+=4){
    float u4[4], dt4[4];
#pragma unroll
    for (int q=0;q<4;q++){
      u4[q]  = bs2f(up[(size_t)(tg+q)*DINNER]);
      dt4[q] = dtp[(size_t)(tg+q)*DINNER];
    }
#pragma unroll
    for (int q=0;q<4;q++){
      const float* Bv = bc + (tg+q)*GCOLS + DTRANK;  // uniform -> s_load
      float4 B0 = *(const float4*)(Bv+0), B1 = *(const float4*)(Bv+4);
      float4 B2 = *(const float4*)(Bv+8), B3 = *(const float4*)(Bv+12);
      float Bf[NSTATE] = {B0.x,B0.y,B0.z,B0.w, B1.x,B1.y,B1.z,B1.w,
                          B2.x,B2.y,B2.z,B2.w, B3.x,B3.y,B3.z,B3.w};
      float dt = dt4[q], du = dt*u4[q];
#pragma unroll
      for (int n=0;n<NSTATE;n++){
        float w = EXP2F(dt * A2[n]);
        h[n] = h[n]*w + du * Bf[n];
      }
    }
  }
  size_t ob = ((size_t)(bd*NCHUNK + c) * NSTATE) * DINNER + d;
#pragma unroll
  for (int n=0;n<NSTATE;n++)
    hLb[ob + (size_t)n*DINNER] = h[n];
}

// Pass B: serial combine over chunks; W reconstructed from sum_dt; hLb -> chunk-initial h0
__launch_bounds__(256)
__global__ void chunk_comb_k(const float* __restrict__ sums, const float* __restrict__ A_log,
                             float* __restrict__ hLb)
{
  int id = blockIdx.x*256 + threadIdx.x;    // (dir*4+b)*768+d
  int d = id % DINNER;
  int bd = id / DINNER;
  float A2[NSTATE];
#pragma unroll
  for (int n=0;n<NSTATE;n++)
    A2[n] = -__expf(A_log[d*NSTATE + n]) * 1.44269504f;
  float h[NSTATE] = {};
  for (int c=0; c<NCHUNK; c++){
    size_t ob = ((size_t)(bd*NCHUNK + c) * NSTATE) * DINNER + d;
    float sdt = sums[(size_t)(bd*NCHUNK + c)*DINNER + d];
#pragma unroll
    for (int n=0;n<NSTATE;n++){
      float Wc = EXP2F(A2[n] * sdt);
      float hL = hLb[ob + (size_t)n*DINNER];
      float h0 = h[n];
      h[n] = Wc*h0 + hL;
      hLb[ob + (size_t)n*DINNER] = h0;
    }
  }
}

// Pass C: replay from h0 using cached dt, emit y, scatter-add token-space
__launch_bounds__(256)
__global__ void chunk_emit_k(const short* __restrict__ ucv_b,
                             const float* __restrict__ xdb, const float* __restrict__ A_log,
                             const float* __restrict__ dt_sv,
                             const float* __restrict__ Dp, const float* __restrict__ h0b,
                             float* __restrict__ acc)
{
  const int d  = blockIdx.x * 256 + threadIdx.x;
  const int c  = blockIdx.y;
  const int bd = blockIdx.z;
  const int b  = bd & 3, dir = bd >> 2;

  float A2[NSTATE];
#pragma unroll
  for (int n=0;n<NSTATE;n++)
    A2[n] = -__expf(A_log[d*NSTATE + n]) * 1.44269504f;
  float Dd = Dp[d];

  const size_t rowbase = (size_t)bd*1024 + (size_t)c*TCHUNK;
  const short* up  = ucv_b + rowbase*DINNER + d;
  const float* bc  = xdb + rowbase*GCOLS;            // block-uniform
  const float* dtp = dt_sv + rowbase*DINNER + d;
  float* ab = acc + (size_t)b*1024*DINNER + d;

  float h[NSTATE];
  size_t ob = ((size_t)(bd*NCHUNK + c) * NSTATE) * DINNER + d;
#pragma unroll
  for (int n=0;n<NSTATE;n++) h[n] = h0b[ob + (size_t)n*DINNER];

  const int t0 = c * TCHUNK;
  for (int tg=0; tg<TCHUNK; tg+=4){
    float u4[4], dt4[4];
#pragma unroll
    for (int q=0;q<4;q++){
      u4[q]  = bs2f(up[(size_t)(tg+q)*DINNER]);
      dt4[q] = dtp[(size_t)(tg+q)*DINNER];
    }
#pragma unroll
    for (int q=0;q<4;q++){
      const float* Bv = bc + (tg+q)*GCOLS + DTRANK;  // uniform -> s_load
      float4 B0 = *(const float4*)(Bv+0), B1 = *(const float4*)(Bv+4);
      float4 B2 = *(const float4*)(Bv+8), B3 = *(const float4*)(Bv+12);
      float4 C0 = *(const float4*)(Bv+16), C1 = *(const float4*)(Bv+20);
      float4 C2 = *(const float4*)(Bv+24), C3 = *(const float4*)(Bv+28);
      float Bf[NSTATE] = {B0.x,B0.y,B0.z,B0.w, B1.x,B1.y,B1.z,B1.w,
                          B2.x,B2.y,B2.z,B2.w, B3.x,B3.y,B3.z,B3.w};
      float Cf[NSTATE] = {C0.x,C0.y,C0.z,C0.w, C1.x,C1.y,C1.z,C1.w,
                          C2.x,C2.y,C2.z,C2.w, C3.x,C3.y,C3.z,C3.w};
      float dt = dt4[q], u = u4[q], du = dt*u;
      float y = 0.f;
#pragma unroll
      for (int n=0;n<NSTATE;n++){
        float w = EXP2F(dt * A2[n]);
        h[n] = h[n]*w + du * Bf[n];
        y = __builtin_fmaf(h[n], Cf[n], y);
      }
      int tok = perm_tok(dir, t0 + tg + q);
      atomicAdd(ab + (size_t)tok*DINNER, y + u*Dd);
    }
  }
}

// acc *= silu(z); also emit bf16 (z read from bf16 xz)
__global__ void combine_k(float* __restrict__ acc, const short* __restrict__ xzb,
                          short* __restrict__ acc_b)
{
  int id = blockIdx.x*256 + threadIdx.x;     // < MROWS*DINNER
  int row = id / DINNER;
  int d = id - row*DINNER;
  float z = bs2f(xzb[(size_t)row*1536 + DINNER + d]);
  float v = acc[id] * silu_f(z);
  acc[id] = v;
  acc_b[id] = f2bs(v);
}

// layernorm over 384; fp32 out + bf16 out
__launch_bounds__(256)
__global__ void ln384_k(const float* __restrict__ in, float* __restrict__ out,
                        const float* __restrict__ w, const float* __restrict__ b,
                        short* __restrict__ bout)
{
  int wv = threadIdx.x >> 6, lane = threadIdx.x & 63;
  size_t row = (size_t)blockIdx.x * 4 + wv;
  const float* ip = in + row * DMODEL;
  float v[6];
#pragma unroll
  for (int k=0;k<6;k++) v[k] = ip[lane + 64*k];
  float s = 0.f;
#pragma unroll
  for (int k=0;k<6;k++) s += v[k];
#pragma unroll
  for (int o=32;o>0;o>>=1) s += __shfl_xor(s, o);
  float mu = s * (1.f/DMODEL);
  float ss = 0.f;
#pragma unroll
  for (int k=0;k<6;k++){ float dd = v[k]-mu; ss += dd*dd; }
#pragma unroll
  for (int o=32;o>0;o>>=1) ss += __shfl_xor(ss, o);
  float inv = rsqrtf(ss*(1.f/DMODEL) + 1e-5f);
  float* op = out + row * DMODEL;
  short* bp = bout + row * DMODEL;
#pragma unroll
  for (int k=0;k<6;k++){
    int c = lane + 64*k;
    float r = (v[k]-mu)*inv*w[c] + b[c];
    op[c] = r;
    bp[c] = f2bs(r);
  }
}

// pixel-shuffle gather + layernorm over 192 + fp32 store
__launch_bounds__(256)
__global__ void peln_k(const float* __restrict__ xe, const float* __restrict__ w,
                       const float* __restrict__ b, float* __restrict__ out)
{
  int wv = threadIdx.x >> 6, lane = threadIdx.x & 63;
  int row = blockIdx.x * 4 + wv;          // b*4096 + h2*64 + w2
  int bb = row >> 12;
  int r2 = row & 4095;
  int h2 = r2 >> 6, w2 = r2 & 63;
  int h = h2 >> 1, s1 = h2 & 1, w_ = w2 >> 1, s2 = w2 & 1;
  const float* ip = xe + ((size_t)(bb*1024 + h*32 + w_))*768 + (s1*2+s2)*192;
  float v[3];
#pragma unroll
  for (int k=0;k<3;k++) v[k] = ip[lane + 64*k];
  float s = v[0]+v[1]+v[2];
#pragma unroll
  for (int o=32;o>0;o>>=1) s += __shfl_xor(s, o);
  float mu = s * (1.f/192);
  float ss = 0.f;
#pragma unroll
  for (int k=0;k<3;k++){ float dd=v[k]-mu; ss+=dd*dd; }
#pragma unroll
  for (int o=32;o>0;o>>=1) ss += __shfl_xor(ss, o);
  float inv = rsqrtf(ss*(1.f/192) + 1e-5f);
  float* op = out + (size_t)row * 192;
#pragma unroll
  for (int k=0;k<3;k++){ int c = lane + 64*k; op[c] = (v[k]-mu)*inv*w[c] + b[c]; }
}

extern "C" void kernel_launch(void* const* d_in, const int* in_sizes, int n_in,
                              void* d_out, int out_size, void* d_ws, size_t ws_size,
                              hipStream_t stream)
{
  const float* x_in   = (const float*)d_in[0];
  const float* in_w   = (const float*)d_in[1];
  const float* conv_w = (const float*)d_in[2];
  const float* conv_b = (const float*)d_in[3];
  const float* xp_w   = (const float*)d_in[4];
  const float* dt_w   = (const float*)d_in[5];
  const float* dt_b   = (const float*)d_in[6];
  const float* A_log  = (const float*)d_in[7];
  const float* Dp     = (const float*)d_in[8];
  const float* mn_w   = (const float*)d_in[9];
  const float* mn_b   = (const float*)d_in[10];
  const float* mout_w = (const float*)d_in[11];
  const float* bp_w   = (const float*)d_in[12];
  const float* bp_b   = (const float*)d_in[13];
  const float* ln_w   = (const float*)d_in[14];
  const float* ln_b   = (const float*)d_in[15];
  const float* exp_w  = (const float*)d_in[16];
  const float* pe_w   = (const float*)d_in[17];
  const float* pe_b   = (const float*)d_in[18];

  float* ws = (float*)d_ws;
  // layout in float units
  float* xcur = ws;                                      // 1,572,864
  short* xz_b = (short*)(xcur + 1572864);                // 6,291,456 shorts
  short* ucv_b = (short*)(xcur + 1572864 + 3145728);     // 12,582,912 shorts
  float* xdb  = xcur + 1572864 + 3145728 + 6291456;      // 917,504
  float* scratch = xdb + 917504;                         // 12,582,912 (dt_sv | t3|t2b|acc_b)
  float* acc  = scratch + 12582912;                      // 3,145,728
  float* big  = acc + 3145728;                           // 6,291,456 (t1|t2 or hLb)
  float* t1   = big;
  float* t2   = t1 + 1572864;
  float* hLb  = big;
  short* in_w_b   = (short*)(big + 6291456);
  short* xp_w_b   = in_w_b + (size_t)2*1536*DMODEL;
  short* mout_w_b = xp_w_b + (size_t)2*GCOLS*DINNER;
  short* bp_w_b   = mout_w_b + (size_t)2*DMODEL*DINNER;
  short* exp_w_b  = bp_w_b + (size_t)2*DMODEL*DMODEL;
  float* sums     = (float*)(exp_w_b + (size_t)2*DMODEL*DMODEL);  // 393,216 f
  short* xcur_b   = (short*)(sums + 393216);             // 3,145,728 sh
  // aliases inside scratch (scan phase: dt_sv; post-scan: t3/t2b/acc_b)
  float* dt_sv = scratch;                                // 16384*768 = 12,582,912 f exactly
  float* t3    = scratch;
  short* t2b   = (short*)(scratch + (size_t)2*1024*1024);
  short* acc_b = (short*)(scratch + (size_t)3*1024*1024 + 262144);
  float* xe    = acc;

  // weight conversions (single batched launch)
  {
    int s0 = 2*1536*DMODEL, s1 = 2*GCOLS*DINNER, s2 = 2*DMODEL*DINNER,
        s3 = 2*DMODEL*DMODEL, s4 = 2*DMODEL*DMODEL;
    int tot = s0+s1+s2+s3+s4;
    f2b5_k<<<dim3((tot+255)/256), dim3(256), 0, stream>>>(
        in_w, xp_w, mout_w, bp_w, exp_w, in_w_b, s0, s1, s2, s3, s4);
  }
  cvt_dual_k<<<dim3((MROWS*DMODEL)/256), dim3(256), 0, stream>>>(x_in, xcur, xcur_b, MROWS*DMODEL);

  for (int i = 0; i < 2; i++) {
    // xz_b = bf16( x @ in_w^T )  (M=4096, N=1536, K=384)  [MFMA, bf16 out]
    gemm_mfma_bout_k<<<dim3(24,64), dim3(256), 0, stream>>>(
        xcur_b, DMODEL, in_w_b + (size_t)i*1536*DMODEL, DMODEL,
        xz_b, 1536, 1536, DMODEL);

    // depthwise conv + silu (bf16 in/out)
    conv_k<<<dim3((4*MROWS*DINNER)/256), dim3(256), 0, stream>>>(
        xz_b, conv_w + (size_t)i*DINNER*4, conv_b + (size_t)i*DINNER, ucv_b);

    // xdb = u @ xp_w^T  (M=16384, N=56, K=768)  [MFMA, merged dirs]
    gemm_mfma_k<0><<<dim3(1,256), dim3(256), 0, stream>>>(
        ucv_b, DINNER, xp_w_b + (size_t)i*GCOLS*DINNER, DINNER,
        xdb, GCOLS, GCOLS, DINNER, nullptr, nullptr);

    // dt (fp32) + per-chunk sums
    dt_k<<<dim3(3, NCHUNK, 16), dim3(256), 0, stream>>>(
        xdb, dt_w + (size_t)i*DINNER*DTRANK, dt_b + (size_t)i*DINNER, dt_sv, sums);

    hipMemsetAsync(acc, 0, (size_t)MROWS*DINNER*sizeof(float), stream);
    chunk_scan_k<<<dim3(3, NCHUNK, 16), dim3(256), 0, stream>>>(
        ucv_b, xdb, A_log + (size_t)i*DINNER*NSTATE, dt_sv, hLb);
    chunk_comb_k<<<dim3(48), dim3(256), 0, stream>>>(sums, A_log + (size_t)i*DINNER*NSTATE, hLb);
    chunk_emit_k<<<dim3(3, NCHUNK, 16), dim3(256), 0, stream>>>(
        ucv_b, xdb, A_log + (size_t)i*DINNER*NSTATE,
        dt_sv, Dp + (size_t)i*DINNER, hLb, acc);
    combine_k<<<dim3((MROWS*DINNER)/256), dim3(256), 0, stream>>>(acc, xz_b, acc_b);

    // t1 = ymix @ mout_w^T  (N=384, K=768)  [MFMA]
    gemm_mfma_k<0><<<dim3(6,64), dim3(256), 0, stream>>>(
        acc_b, DINNER, mout_w_b + (size_t)i*DMODEL*DINNER, DINNER,
        t1, DMODEL, DMODEL, DINNER, nullptr, nullptr);
    ln384_k<<<dim3(1024), dim3(256), 0, stream>>>(t1, t2, mn_w + (size_t)i*DMODEL, mn_b + (size_t)i*DMODEL, t2b);
    // t3 = xcur + t2 @ bp_w^T + bp_b  (N=384, K=384)  [MFMA + bias + res]
    gemm_mfma_k<2><<<dim3(6,64), dim3(256), 0, stream>>>(
        t2b, DMODEL, bp_w_b + (size_t)i*DMODEL*DMODEL, DMODEL,
        t3, DMODEL, DMODEL, DMODEL, bp_b + (size_t)i*DMODEL, xcur);
    ln384_k<<<dim3(1024), dim3(256), 0, stream>>>(t3, xcur, ln_w + (size_t)i*DMODEL, ln_b + (size_t)i*DMODEL, xcur_b);
  }

  // xe = x @ exp_w^T  (M=4096, N=768, K=384)  [MFMA]
  gemm_mfma_k<0><<<dim3(12,64), dim3(256), 0, stream>>>(
      xcur_b, DMODEL, exp_w_b, DMODEL, xe, 2*DMODEL, 2*DMODEL, DMODEL, nullptr, nullptr);
  // pixel-shuffle + LN(192) -> fp32 out
  peln_k<<<dim3(4096), dim3(256), 0, stream>>>(xe, pe_w, pe_b, (float*)d_out);
}

// Round 13
// 671.558 us; speedup vs baseline: 1.2210x; 1.1283x over previous
//
#include <hip/hip_runtime.h>
#include <hip/hip_bf16.h>
#include <math.h>

typedef __hip_bfloat16 bf16;

#define MROWS 4096      // BATCH * L
#define DMODEL 384
#define DINNER 768
#define GCOLS 56        // DT_RANK + 2*D_STATE
#define DTRANK 24
#define NSTATE 16
#define NCHUNK 32
#define TCHUNK 32
#define CT 8            // conv: t-outputs per thread

typedef __attribute__((ext_vector_type(8))) short bf16x8;
typedef __attribute__((ext_vector_type(4))) float f32x4;

#if __has_builtin(__builtin_amdgcn_exp2f)
#define EXP2F(x) __builtin_amdgcn_exp2f(x)
#else
#define EXP2F(x) exp2f(x)
#endif

__device__ __forceinline__ float silu_f(float x){ return x / (1.f + __expf(-x)); }
__device__ __forceinline__ float softplus_f(float x){
  return (x > 20.f) ? x : __logf(1.f + __expf(x));
}
__device__ __forceinline__ short f2bs(float x){
  bf16 h = __float2bfloat16(x);
  return *(short*)&h;
}
__device__ __forceinline__ float bs2f(short s){
  bf16 h = *(bf16*)&s;
  return __bfloat162float(h);
}

// seq index t -> token index, per direction
__device__ __forceinline__ int perm_tok(int dir, int t){
  if (dir == 0) return t;
  if (dir == 2) return 1023 - t;
  int tt = (dir == 1) ? t : (1023 - t);
  int i = tt >> 5, j = tt & 31;
  return ((31 - j) << 5) | i;   // token = (31-j)*32 + i
}

// ---------------- bf16 MFMA GEMM: C[M,N] = A[M,K] @ W[N,K]^T (fp32 accum) ----
// EPI 0: none (fp32 out); 2: + bias[n] + res[m,n] (fp32 out)
template<int EPI>
__launch_bounds__(256)
__global__ void gemm_mfma_k(const short* __restrict__ A, int lda,
                            const short* __restrict__ W, int ldw,
                            float* __restrict__ C, int ldc,
                            int Ndim, int Kdim,
                            const float* __restrict__ bias,
                            const float* __restrict__ res)
{
  const int wv = threadIdx.x >> 6, lane = threadIdx.x & 63;
  const int m0 = blockIdx.y * 64;
  const int n0 = blockIdx.x * 64 + wv * 16;
  const int lm = lane & 15;          // fragment row (A-m / B-n)
  const int kq = (lane >> 4) * 8;    // fragment k offset
  f32x4 acc0 = {0.f,0.f,0.f,0.f}, acc1 = acc0, acc2 = acc0, acc3 = acc0;
  const bool nok = (n0 + lm) < Ndim;
  const short* ap = A + (size_t)(m0 + lm) * lda + kq;
  const short* wp = W + (size_t)(nok ? (n0 + lm) : 0) * ldw + kq;
  const size_t ar16 = (size_t)16 * lda;
  const bf16x8 bz = {0,0,0,0,0,0,0,0};

  for (int k0 = 0; k0 < Kdim; k0 += 32) {
    bf16x8 b = bz;
    if (nok) b = *(const bf16x8*)(wp + k0);
    bf16x8 a0 = *(const bf16x8*)(ap + k0);
    bf16x8 a1 = *(const bf16x8*)(ap + ar16 + k0);
    bf16x8 a2 = *(const bf16x8*)(ap + 2*ar16 + k0);
    bf16x8 a3 = *(const bf16x8*)(ap + 3*ar16 + k0);
    acc0 = __builtin_amdgcn_mfma_f32_16x16x32_bf16(a0, b, acc0, 0, 0, 0);
    acc1 = __builtin_amdgcn_mfma_f32_16x16x32_bf16(a1, b, acc1, 0, 0, 0);
    acc2 = __builtin_amdgcn_mfma_f32_16x16x32_bf16(a2, b, acc2, 0, 0, 0);
    acc3 = __builtin_amdgcn_mfma_f32_16x16x32_bf16(a3, b, acc3, 0, 0, 0);
  }

  const int ncol = n0 + lm;                 // C/D: col = lane&15
  if (ncol < Ndim) {
    const int mr = m0 + (lane >> 4) * 4;    // C/D: row = quad*4 + reg
    f32x4 av[4] = {acc0, acc1, acc2, acc3};
#pragma unroll
    for (int mt = 0; mt < 4; mt++) {
#pragma unroll
      for (int reg = 0; reg < 4; reg++) {
        int m = mr + mt*16 + reg;
        float v = av[mt][reg];
        if (EPI == 2) v += bias[ncol] + res[(size_t)m*ldc + ncol];
        C[(size_t)m*ldc + ncol] = v;
      }
    }
  }
}

// same GEMM but bf16 output (for in_proj -> xz_b)
__launch_bounds__(256)
__global__ void gemm_mfma_bout_k(const short* __restrict__ A, int lda,
                                 const short* __restrict__ W, int ldw,
                                 short* __restrict__ C, int ldc,
                                 int Ndim, int Kdim)
{
  const int wv = threadIdx.x >> 6, lane = threadIdx.x & 63;
  const int m0 = blockIdx.y * 64;
  const int n0 = blockIdx.x * 64 + wv * 16;
  const int lm = lane & 15;
  const int kq = (lane >> 4) * 8;
  f32x4 acc0 = {0.f,0.f,0.f,0.f}, acc1 = acc0, acc2 = acc0, acc3 = acc0;
  const bool nok = (n0 + lm) < Ndim;
  const short* ap = A + (size_t)(m0 + lm) * lda + kq;
  const short* wp = W + (size_t)(nok ? (n0 + lm) : 0) * ldw + kq;
  const size_t ar16 = (size_t)16 * lda;
  const bf16x8 bz = {0,0,0,0,0,0,0,0};

  for (int k0 = 0; k0 < Kdim; k0 += 32) {
    bf16x8 b = bz;
    if (nok) b = *(const bf16x8*)(wp + k0);
    bf16x8 a0 = *(const bf16x8*)(ap + k0);
    bf16x8 a1 = *(const bf16x8*)(ap + ar16 + k0);
    bf16x8 a2 = *(const bf16x8*)(ap + 2*ar16 + k0);
    bf16x8 a3 = *(const bf16x8*)(ap + 3*ar16 + k0);
    acc0 = __builtin_amdgcn_mfma_f32_16x16x32_bf16(a0, b, acc0, 0, 0, 0);
    acc1 = __builtin_amdgcn_mfma_f32_16x16x32_bf16(a1, b, acc1, 0, 0, 0);
    acc2 = __builtin_amdgcn_mfma_f32_16x16x32_bf16(a2, b, acc2, 0, 0, 0);
    acc3 = __builtin_amdgcn_mfma_f32_16x16x32_bf16(a3, b, acc3, 0, 0, 0);
  }

  const int ncol = n0 + lm;
  if (ncol < Ndim) {
    const int mr = m0 + (lane >> 4) * 4;
    f32x4 av[4] = {acc0, acc1, acc2, acc3};
#pragma unroll
    for (int mt = 0; mt < 4; mt++) {
#pragma unroll
      for (int reg = 0; reg < 4; reg++) {
        int m = mr + mt*16 + reg;
        C[(size_t)m*ldc + ncol] = f2bs(av[mt][reg]);
      }
    }
  }
}

// ---------------- conversions / misc ----------------
__global__ void f2b5_k(const float* __restrict__ a0, const float* __restrict__ a1,
                       const float* __restrict__ a2, const float* __restrict__ a3,
                       const float* __restrict__ a4, short* __restrict__ o,
                       int s0, int s1, int s2, int s3, int s4)
{
  int id = blockIdx.x*256 + threadIdx.x;
  int e0 = s0, e1 = e0+s1, e2 = e1+s2, e3 = e2+s3, e4 = e3+s4;
  if (id >= e4) return;
  float v;
  if      (id < e0) v = a0[id];
  else if (id < e1) v = a1[id-e0];
  else if (id < e2) v = a2[id-e1];
  else if (id < e3) v = a3[id-e2];
  else              v = a4[id-e3];
  o[id] = f2bs(v);
}
__global__ void cvt_dual_k(const float* __restrict__ in, float* __restrict__ of,
                           short* __restrict__ ob, int n){
  int id = blockIdx.x*256 + threadIdx.x;
  if (id < n) { float v = in[id]; of[id] = v; ob[id] = f2bs(v); }
}

// depthwise causal conv (k=4): register-blocked, one thread = d-pair x CT t-steps
// grid (128, 16), block 384; bf16 in/out, packed 4B loads/stores
__launch_bounds__(384)
__global__ void conv_k(const short* __restrict__ xzb, const float* __restrict__ cw,
                       const float* __restrict__ cb, short* __restrict__ ucv_b)
{
  const int d2 = threadIdx.x;            // 0..383 (d = 2*d2, d+1)
  const int t0 = blockIdx.x * CT;        // 0..1016
  const int bd = blockIdx.y;             // dir*4+b
  const int b_ = bd & 3, dir = bd >> 2;
  const int d  = d2 * 2;

  float w0[4], w1[4];
#pragma unroll
  for (int j=0;j<4;j++){ w0[j] = cw[d*4+j]; w1[j] = cw[(d+1)*4+j]; }
  const float cb0 = cb[d], cb1 = cb[d+1];

  const short* base = xzb + (size_t)b_*1024*1536 + d;
  float ua[CT+3][2];
#pragma unroll
  for (int j=0;j<CT+3;j++){
    int tm = t0 - 3 + j;
    float v0 = 0.f, v1 = 0.f;
    if (tm >= 0){
      int tok = perm_tok(dir, tm);       // block-uniform
      unsigned int pk = *(const unsigned int*)(base + (size_t)tok*1536);
      v0 = bs2f((short)(pk & 0xffff));
      v1 = bs2f((short)(pk >> 16));
    }
    ua[j][0] = v0; ua[j][1] = v1;
  }

  short* op = ucv_b + ((size_t)bd*1024 + t0)*DINNER + d;
#pragma unroll
  for (int tt=0; tt<CT; tt++){
    float s0 = cb0, s1 = cb1;
#pragma unroll
    for (int j=0;j<4;j++){
      s0 = __builtin_fmaf(w0[j], ua[tt+j][0], s0);
      s1 = __builtin_fmaf(w1[j], ua[tt+j][1], s1);
    }
    unsigned int r = (unsigned int)(unsigned short)f2bs(silu_f(s0))
                   | ((unsigned int)(unsigned short)f2bs(silu_f(s1)) << 16);
    *(unsigned int*)(op + (size_t)tt*DINNER) = r;
  }
}

// ============ chunked selective scan ============
// dt_k: grid (3, NCHUNK, 16): dt = softplus(xdb[:, :24] @ dt_w[d] + dt_b[d])
__launch_bounds__(256)
__global__ void dt_k(const float* __restrict__ xdb,
                     const float* __restrict__ dt_w, const float* __restrict__ dt_b,
                     float* __restrict__ dt_sv, float* __restrict__ sums)
{
  const int d  = blockIdx.x * 256 + threadIdx.x;   // 0..767
  const int c  = blockIdx.y;
  const int bd = blockIdx.z;

  float w24[DTRANK];
#pragma unroll
  for (int r=0;r<DTRANK;r++) w24[r] = dt_w[d*DTRANK + r];
  const float bias = dt_b[d];

  const size_t rowbase = (size_t)bd*1024 + (size_t)c*TCHUNK;
  const float* bc = xdb + rowbase*GCOLS;           // block-uniform
  float* dtp = dt_sv + rowbase*DINNER + d;

  float sdt = 0.f;
  for (int tt=0; tt<TCHUNK; tt++){
    const float* Xr = bc + tt*GCOLS;               // uniform -> s_load
    float v = bias;
#pragma unroll
    for (int r=0;r<DTRANK;r++) v = __builtin_fmaf(Xr[r], w24[r], v);
    float dt = softplus_f(v);
    dtp[(size_t)tt*DINNER] = dt;
    sdt += dt;
  }
  sums[(size_t)(bd*NCHUNK + c)*DINNER + d] = sdt;
}

// Pass A: grid (3, NCHUNK, 16): local scan from 0 -> hL[n], dt from cache
__launch_bounds__(256)
__global__ void chunk_scan_k(const short* __restrict__ ucv_b,
                             const float* __restrict__ xdb, const float* __restrict__ A_log,
                             const float* __restrict__ dt_sv,
                             float* __restrict__ hLb)
{
  const int d  = blockIdx.x * 256 + threadIdx.x;   // 0..767
  const int c  = blockIdx.y;                       // chunk
  const int bd = blockIdx.z;                       // dir*4+b

  float A2[NSTATE];
#pragma unroll
  for (int n=0;n<NSTATE;n++)
    A2[n] = -__expf(A_log[d*NSTATE + n]) * 1.44269504f;

  const size_t rowbase = (size_t)bd*1024 + (size_t)c*TCHUNK;
  const short* up  = ucv_b + rowbase*DINNER + d;
  const float* bc  = xdb + rowbase*GCOLS;            // block-uniform
  const float* dtp = dt_sv + rowbase*DINNER + d;

  float h[NSTATE] = {};

  for (int tg=0; tg<TCHUNK; tg+=4){
    float u4[4], dt4[4];
#pragma unroll
    for (int q=0;q<4;q++){
      u4[q]  = bs2f(up[(size_t)(tg+q)*DINNER]);
      dt4[q] = dtp[(size_t)(tg+q)*DINNER];
    }
#pragma unroll
    for (int q=0;q<4;q++){
      const float* Bv = bc + (tg+q)*GCOLS + DTRANK;  // uniform -> s_load
      float4 B0 = *(const float4*)(Bv+0), B1 = *(const float4*)(Bv+4);
      float4 B2 = *(const float4*)(Bv+8), B3 = *(const float4*)(Bv+12);
      float Bf[NSTATE] = {B0.x,B0.y,B0.z,B0.w, B1.x,B1.y,B1.z,B1.w,
                          B2.x,B2.y,B2.z,B2.w, B3.x,B3.y,B3.z,B3.w};
      float dt = dt4[q], du = dt*u4[q];
#pragma unroll
      for (int n=0;n<NSTATE;n++){
        float w = EXP2F(dt * A2[n]);
        h[n] = h[n]*w + du * Bf[n];
      }
    }
  }
  size_t ob = ((size_t)(bd*NCHUNK + c) * NSTATE) * DINNER + d;
#pragma unroll
  for (int n=0;n<NSTATE;n++)
    hLb[ob + (size_t)n*DINNER] = h[n];
}

// Pass B: serial combine over chunks; W reconstructed from sum_dt; hLb -> chunk-initial h0
__launch_bounds__(256)
__global__ void chunk_comb_k(const float* __restrict__ sums, const float* __restrict__ A_log,
                             float* __restrict__ hLb)
{
  int id = blockIdx.x*256 + threadIdx.x;    // (dir*4+b)*768+d
  int d = id % DINNER;
  int bd = id / DINNER;
  float A2[NSTATE];
#pragma unroll
  for (int n=0;n<NSTATE;n++)
    A2[n] = -__expf(A_log[d*NSTATE + n]) * 1.44269504f;
  float h[NSTATE] = {};
  for (int c=0; c<NCHUNK; c++){
    size_t ob = ((size_t)(bd*NCHUNK + c) * NSTATE) * DINNER + d;
    float sdt = sums[(size_t)(bd*NCHUNK + c)*DINNER + d];
#pragma unroll
    for (int n=0;n<NSTATE;n++){
      float Wc = EXP2F(A2[n] * sdt);
      float hL = hLb[ob + (size_t)n*DINNER];
      float h0 = h[n];
      h[n] = Wc*h0 + hL;
      hLb[ob + (size_t)n*DINNER] = h0;
    }
  }
}

// Pass C: replay from h0 using cached dt, emit y, scatter-add token-space
__launch_bounds__(256)
__global__ void chunk_emit_k(const short* __restrict__ ucv_b,
                             const float* __restrict__ xdb, const float* __restrict__ A_log,
                             const float* __restrict__ dt_sv,
                             const float* __restrict__ Dp, const float* __restrict__ h0b,
                             float* __restrict__ acc)
{
  const int d  = blockIdx.x * 256 + threadIdx.x;
  const int c  = blockIdx.y;
  const int bd = blockIdx.z;
  const int b  = bd & 3, dir = bd >> 2;

  float A2[NSTATE];
#pragma unroll
  for (int n=0;n<NSTATE;n++)
    A2[n] = -__expf(A_log[d*NSTATE + n]) * 1.44269504f;
  float Dd = Dp[d];

  const size_t rowbase = (size_t)bd*1024 + (size_t)c*TCHUNK;
  const short* up  = ucv_b + rowbase*DINNER + d;
  const float* bc  = xdb + rowbase*GCOLS;            // block-uniform
  const float* dtp = dt_sv + rowbase*DINNER + d;
  float* ab = acc + (size_t)b*1024*DINNER + d;

  float h[NSTATE];
  size_t ob = ((size_t)(bd*NCHUNK + c) * NSTATE) * DINNER + d;
#pragma unroll
  for (int n=0;n<NSTATE;n++) h[n] = h0b[ob + (size_t)n*DINNER];

  const int t0 = c * TCHUNK;
  for (int tg=0; tg<TCHUNK; tg+=4){
    float u4[4], dt4[4];
#pragma unroll
    for (int q=0;q<4;q++){
      u4[q]  = bs2f(up[(size_t)(tg+q)*DINNER]);
      dt4[q] = dtp[(size_t)(tg+q)*DINNER];
    }
#pragma unroll
    for (int q=0;q<4;q++){
      const float* Bv = bc + (tg+q)*GCOLS + DTRANK;  // uniform -> s_load
      float4 B0 = *(const float4*)(Bv+0), B1 = *(const float4*)(Bv+4);
      float4 B2 = *(const float4*)(Bv+8), B3 = *(const float4*)(Bv+12);
      float4 C0 = *(const float4*)(Bv+16), C1 = *(const float4*)(Bv+20);
      float4 C2 = *(const float4*)(Bv+24), C3 = *(const float4*)(Bv+28);
      float Bf[NSTATE] = {B0.x,B0.y,B0.z,B0.w, B1.x,B1.y,B1.z,B1.w,
                          B2.x,B2.y,B2.z,B2.w, B3.x,B3.y,B3.z,B3.w};
      float Cf[NSTATE] = {C0.x,C0.y,C0.z,C0.w, C1.x,C1.y,C1.z,C1.w,
                          C2.x,C2.y,C2.z,C2.w, C3.x,C3.y,C3.z,C3.w};
      float dt = dt4[q], u = u4[q], du = dt*u;
      float y = 0.f;
#pragma unroll
      for (int n=0;n<NSTATE;n++){
        float w = EXP2F(dt * A2[n]);
        h[n] = h[n]*w + du * Bf[n];
        y = __builtin_fmaf(h[n], Cf[n], y);
      }
      int tok = perm_tok(dir, t0 + tg + q);
      atomicAdd(ab + (size_t)tok*DINNER, y + u*Dd);
    }
  }
}

// acc *= silu(z); also emit bf16 (z read from bf16 xz)
__global__ void combine_k(float* __restrict__ acc, const short* __restrict__ xzb,
                          short* __restrict__ acc_b)
{
  int id = blockIdx.x*256 + threadIdx.x;     // < MROWS*DINNER
  int row = id / DINNER;
  int d = id - row*DINNER;
  float z = bs2f(xzb[(size_t)row*1536 + DINNER + d]);
  float v = acc[id] * silu_f(z);
  acc[id] = v;
  acc_b[id] = f2bs(v);
}

// layernorm over 384; fp32 out + bf16 out
__launch_bounds__(256)
__global__ void ln384_k(const float* __restrict__ in, float* __restrict__ out,
                        const float* __restrict__ w, const float* __restrict__ b,
                        short* __restrict__ bout)
{
  int wv = threadIdx.x >> 6, lane = threadIdx.x & 63;
  size_t row = (size_t)blockIdx.x * 4 + wv;
  const float* ip = in + row * DMODEL;
  float v[6];
#pragma unroll
  for (int k=0;k<6;k++) v[k] = ip[lane + 64*k];
  float s = 0.f;
#pragma unroll
  for (int k=0;k<6;k++) s += v[k];
#pragma unroll
  for (int o=32;o>0;o>>=1) s += __shfl_xor(s, o);
  float mu = s * (1.f/DMODEL);
  float ss = 0.f;
#pragma unroll
  for (int k=0;k<6;k++){ float dd = v[k]-mu; ss += dd*dd; }
#pragma unroll
  for (int o=32;o>0;o>>=1) ss += __shfl_xor(ss, o);
  float inv = rsqrtf(ss*(1.f/DMODEL) + 1e-5f);
  float* op = out + row * DMODEL;
  short* bp = bout + row * DMODEL;
#pragma unroll
  for (int k=0;k<6;k++){
    int c = lane + 64*k;
    float r = (v[k]-mu)*inv*w[c] + b[c];
    op[c] = r;
    bp[c] = f2bs(r);
  }
}

// pixel-shuffle gather + layernorm over 192 + fp32 store
__launch_bounds__(256)
__global__ void peln_k(const float* __restrict__ xe, const float* __restrict__ w,
                       const float* __restrict__ b, float* __restrict__ out)
{
  int wv = threadIdx.x >> 6, lane = threadIdx.x & 63;
  int row = blockIdx.x * 4 + wv;          // b*4096 + h2*64 + w2
  int bb = row >> 12;
  int r2 = row & 4095;
  int h2 = r2 >> 6, w2 = r2 & 63;
  int h = h2 >> 1, s1 = h2 & 1, w_ = w2 >> 1, s2 = w2 & 1;
  const float* ip = xe + ((size_t)(bb*1024 + h*32 + w_))*768 + (s1*2+s2)*192;
  float v[3];
#pragma unroll
  for (int k=0;k<3;k++) v[k] = ip[lane + 64*k];
  float s = v[0]+v[1]+v[2];
#pragma unroll
  for (int o=32;o>0;o>>=1) s += __shfl_xor(s, o);
  float mu = s * (1.f/192);
  float ss = 0.f;
#pragma unroll
  for (int k=0;k<3;k++){ float dd=v[k]-mu; ss+=dd*dd; }
#pragma unroll
  for (int o=32;o>0;o>>=1) ss += __shfl_xor(ss, o);
  float inv = rsqrtf(ss*(1.f/192) + 1e-5f);
  float* op = out + (size_t)row * 192;
#pragma unroll
  for (int k=0;k<3;k++){ int c = lane + 64*k; op[c] = (v[k]-mu)*inv*w[c] + b[c]; }
}

extern "C" void kernel_launch(void* const* d_in, const int* in_sizes, int n_in,
                              void* d_out, int out_size, void* d_ws, size_t ws_size,
                              hipStream_t stream)
{
  const float* x_in   = (const float*)d_in[0];
  const float* in_w   = (const float*)d_in[1];
  const float* conv_w = (const float*)d_in[2];
  const float* conv_b = (const float*)d_in[3];
  const float* xp_w   = (const float*)d_in[4];
  const float* dt_w   = (const float*)d_in[5];
  const float* dt_b   = (const float*)d_in[6];
  const float* A_log  = (const float*)d_in[7];
  const float* Dp     = (const float*)d_in[8];
  const float* mn_w   = (const float*)d_in[9];
  const float* mn_b   = (const float*)d_in[10];
  const float* mout_w = (const float*)d_in[11];
  const float* bp_w   = (const float*)d_in[12];
  const float* bp_b   = (const float*)d_in[13];
  const float* ln_w   = (const float*)d_in[14];
  const float* ln_b   = (const float*)d_in[15];
  const float* exp_w  = (const float*)d_in[16];
  const float* pe_w   = (const float*)d_in[17];
  const float* pe_b   = (const float*)d_in[18];

  float* ws = (float*)d_ws;
  // layout in float units
  float* xcur = ws;                                      // 1,572,864
  short* xz_b = (short*)(xcur + 1572864);                // 6,291,456 shorts
  short* ucv_b = (short*)(xcur + 1572864 + 3145728);     // 12,582,912 shorts
  float* xdb  = xcur + 1572864 + 3145728 + 6291456;      // 917,504
  float* scratch = xdb + 917504;                         // 12,582,912 (dt_sv | t3|t2b|acc_b)
  float* acc  = scratch + 12582912;                      // 3,145,728
  float* big  = acc + 3145728;                           // 6,291,456 (t1|t2 or hLb)
  float* t1   = big;
  float* t2   = t1 + 1572864;
  float* hLb  = big;
  short* in_w_b   = (short*)(big + 6291456);
  short* xp_w_b   = in_w_b + (size_t)2*1536*DMODEL;
  short* mout_w_b = xp_w_b + (size_t)2*GCOLS*DINNER;
  short* bp_w_b   = mout_w_b + (size_t)2*DMODEL*DINNER;
  short* exp_w_b  = bp_w_b + (size_t)2*DMODEL*DMODEL;
  float* sums     = (float*)(exp_w_b + (size_t)2*DMODEL*DMODEL);  // 393,216 f
  short* xcur_b   = (short*)(sums + 393216);             // 3,145,728 sh
  // aliases inside scratch (scan phase: dt_sv; post-scan: t3/t2b/acc_b)
  float* dt_sv = scratch;                                // 16384*768 = 12,582,912 f exactly
  float* t3    = scratch;
  short* t2b   = (short*)(scratch + (size_t)2*1024*1024);
  short* acc_b = (short*)(scratch + (size_t)3*1024*1024 + 262144);
  float* xe    = acc;

  // weight conversions (single batched launch)
  {
    int s0 = 2*1536*DMODEL, s1 = 2*GCOLS*DINNER, s2 = 2*DMODEL*DINNER,
        s3 = 2*DMODEL*DMODEL, s4 = 2*DMODEL*DMODEL;
    int tot = s0+s1+s2+s3+s4;
    f2b5_k<<<dim3((tot+255)/256), dim3(256), 0, stream>>>(
        in_w, xp_w, mout_w, bp_w, exp_w, in_w_b, s0, s1, s2, s3, s4);
  }
  cvt_dual_k<<<dim3((MROWS*DMODEL)/256), dim3(256), 0, stream>>>(x_in, xcur, xcur_b, MROWS*DMODEL);

  for (int i = 0; i < 2; i++) {
    // xz_b = bf16( x @ in_w^T )  (M=4096, N=1536, K=384)  [MFMA, bf16 out]
    gemm_mfma_bout_k<<<dim3(24,64), dim3(256), 0, stream>>>(
        xcur_b, DMODEL, in_w_b + (size_t)i*1536*DMODEL, DMODEL,
        xz_b, 1536, 1536, DMODEL);

    // depthwise conv + silu (register-blocked, bf16 in/out)
    conv_k<<<dim3(1024/CT, 16), dim3(384), 0, stream>>>(
        xz_b, conv_w + (size_t)i*DINNER*4, conv_b + (size_t)i*DINNER, ucv_b);

    // xdb = u @ xp_w^T  (M=16384, N=56, K=768)  [MFMA, merged dirs]
    gemm_mfma_k<0><<<dim3(1,256), dim3(256), 0, stream>>>(
        ucv_b, DINNER, xp_w_b + (size_t)i*GCOLS*DINNER, DINNER,
        xdb, GCOLS, GCOLS, DINNER, nullptr, nullptr);

    // dt (fp32) + per-chunk sums
    dt_k<<<dim3(3, NCHUNK, 16), dim3(256), 0, stream>>>(
        xdb, dt_w + (size_t)i*DINNER*DTRANK, dt_b + (size_t)i*DINNER, dt_sv, sums);

    hipMemsetAsync(acc, 0, (size_t)MROWS*DINNER*sizeof(float), stream);
    chunk_scan_k<<<dim3(3, NCHUNK, 16), dim3(256), 0, stream>>>(
        ucv_b, xdb, A_log + (size_t)i*DINNER*NSTATE, dt_sv, hLb);
    chunk_comb_k<<<dim3(48), dim3(256), 0, stream>>>(sums, A_log + (size_t)i*DINNER*NSTATE, hLb);
    chunk_emit_k<<<dim3(3, NCHUNK, 16), dim3(256), 0, stream>>>(
        ucv_b, xdb, A_log + (size_t)i*DINNER*NSTATE,
        dt_sv, Dp + (size_t)i*DINNER, hLb, acc);
    combine_k<<<dim3((MROWS*DINNER)/256), dim3(256), 0, stream>>>(acc, xz_b, acc_b);

    // t1 = ymix @ mout_w^T  (N=384, K=768)  [MFMA]
    gemm_mfma_k<0><<<dim3(6,64), dim3(256), 0, stream>>>(
        acc_b, DINNER, mout_w_b + (size_t)i*DMODEL*DINNER, DINNER,
        t1, DMODEL, DMODEL, DINNER, nullptr, nullptr);
    ln384_k<<<dim3(1024), dim3(256), 0, stream>>>(t1, t2, mn_w + (size_t)i*DMODEL, mn_b + (size_t)i*DMODEL, t2b);
    // t3 = xcur + t2 @ bp_w^T + bp_b  (N=384, K=384)  [MFMA + bias + res]
    gemm_mfma_k<2><<<dim3(6,64), dim3(256), 0, stream>>>(
        t2b, DMODEL, bp_w_b + (size_t)i*DMODEL*DMODEL, DMODEL,
        t3, DMODEL, DMODEL, DMODEL, bp_b + (size_t)i*DMODEL, xcur);
    ln384_k<<<dim3(1024), dim3(256), 0, stream>>>(t3, xcur, ln_w + (size_t)i*DMODEL, ln_b + (size_t)i*DMODEL, xcur_b);
  }

  // xe = x @ exp_w^T  (M=4096, N=768, K=384)  [MFMA]
  gemm_mfma_k<0><<<dim3(12,64), dim3(256), 0, stream>>>(
      xcur_b, DMODEL, exp_w_b, DMODEL, xe, 2*DMODEL, 2*DMODEL, DMODEL, nullptr, nullptr);
  // pixel-shuffle + LN(192) -> fp32 out
  peln_k<<<dim3(4096), dim3(256), 0, stream>>>(xe, pe_w, pe_b, (float*)d_out);
}